// Round 23
// baseline (151.951 us; speedup 1.0000x reference)
//
#include <hip/hip_runtime.h>
#include <hip/hip_fp16.h>

#define NN 50000
#define NE 1600000
#define EP (NE + NN)
#define INC 64
#define TDIM 32
#define INDIM 96
#define D1 128
#define NEG 0.2f
#define LOG2E 1.44269504f

#define CBSH 7
#define NCB 391               // ceil(NN / 128)
#define GCAP 5120             // mean 4220 + ~13 sigma
#define TILE 4096

#define MT 64                 // gemm0 M-tile rows per block
#define KP 104                // padded K stride (208B rows, 16B aligned)

typedef _Float16 h2v __attribute__((ext_vector_type(2)));
typedef _Float16 f16x8 __attribute__((ext_vector_type(8)));
typedef float f32x4 __attribute__((ext_vector_type(4)));
union H2U { unsigned u; __half2 h; h2v v; };

__device__ __forceinline__ float lrelu(float v) { return v > 0.f ? v : NEG * v; }

// ---- pack Wl|Wr into transposed fp16 B [256][96] + bias concat [256]
__global__ __launch_bounds__(256) void k_wcast(
    const float* __restrict__ Wl, const float* __restrict__ Wr,
    const float* __restrict__ bl, const float* __restrict__ br,
    __half* __restrict__ Btg, float* __restrict__ bcat)
{
    int idx = blockIdx.x * 256 + threadIdx.x;
    if (idx < 256) bcat[idx] = (idx < 128) ? bl[idx] : br[idx - 128];
    if (idx >= 256 * INDIM) return;
    int c = idx / INDIM, k = idx - c * INDIM;
    float v = (c < 128) ? Wl[k * D1 + c] : Wr[k * D1 + (c - 128)];
    Btg[idx] = __float2half(v);
}

// ---- GEMM0 via MFMA: B prefetched to registers; A staged in LDS (13KB)
__global__ __launch_bounds__(256) void k_gemm0m(
    const float* __restrict__ x, const int* __restrict__ ts,
    const float* __restrict__ Wt,
    const __half* __restrict__ Btg, const float* __restrict__ bcat,
    __half* __restrict__ xl0, __half* __restrict__ xr0)
{
    __shared__ _Float16 As[MT][KP];
    const int t = threadIdx.x;
    const int base = blockIdx.x * MT;
    const float4* __restrict__ x4  = reinterpret_cast<const float4*>(x);
    const float4* __restrict__ wt4 = reinterpret_cast<const float4*>(Wt);

    const int lane = t & 63;
    const int w = t >> 6;
    const int lo4 = lane & 15;
    const int hi2 = lane >> 4;

    f16x8 bfr[3][4];
#pragma unroll
    for (int ks = 0; ks < 3; ++ks)
#pragma unroll
        for (int ns = 0; ns < 4; ++ns)
            bfr[ks][ns] = *reinterpret_cast<const f16x8*>(
                Btg + (size_t)(w * 64 + ns * 16 + lo4) * INDIM + ks * 32 + hi2 * 8);

    float4 av0, av1, av2, av3, av4, av5;
#define LOADA(J, AV)                                                   \
    {   int c = t + (J) * 256;                                         \
        int m = c / 24, q = c - m * 24;                                \
        int n = base + m;                                              \
        if (n < NN)                                                    \
            AV = (q < 16) ? x4[(size_t)n * 16 + q]                     \
                          : wt4[(size_t)ts[n] * 8 + (q - 16)];         \
        else AV = make_float4(0.f, 0.f, 0.f, 0.f);                     \
    }
    LOADA(0, av0) LOADA(1, av1) LOADA(2, av2)
    LOADA(3, av3) LOADA(4, av4) LOADA(5, av5)
#undef LOADA
#define WRITEA(J, AV)                                                  \
    {   int c = t + (J) * 256;                                         \
        int m = c / 24, q = c - m * 24;                                \
        h2v p01 = { (_Float16)AV.x, (_Float16)AV.y };                  \
        h2v p23 = { (_Float16)AV.z, (_Float16)AV.w };                  \
        *reinterpret_cast<h2v*>(&As[m][q * 4])     = p01;              \
        *reinterpret_cast<h2v*>(&As[m][q * 4 + 2]) = p23;              \
    }
    WRITEA(0, av0) WRITEA(1, av1) WRITEA(2, av2)
    WRITEA(3, av3) WRITEA(4, av4) WRITEA(5, av5)
#undef WRITEA
    __syncthreads();

    f32x4 acc[4][4] = {};
#pragma unroll
    for (int ks = 0; ks < 3; ++ks) {
        const int kb = ks * 32 + hi2 * 8;
        f16x8 a[4];
#pragma unroll
        for (int ms = 0; ms < 4; ++ms)
            a[ms] = *reinterpret_cast<const f16x8*>(&As[ms * 16 + lo4][kb]);
#pragma unroll
        for (int ms = 0; ms < 4; ++ms)
#pragma unroll
            for (int ns = 0; ns < 4; ++ns)
                acc[ms][ns] = __builtin_amdgcn_mfma_f32_16x16x32_f16(
                    a[ms], bfr[ks][ns], acc[ms][ns], 0, 0, 0);
    }

#pragma unroll
    for (int ms = 0; ms < 4; ++ms) {
#pragma unroll
        for (int ns = 0; ns < 4; ++ns) {
            int col = w * 64 + ns * 16 + lo4;
            float bv = bcat[col];
            __half* outp = (col & 128) ? xr0 : xl0;
            int cc = col & 127;
#pragma unroll
            for (int r = 0; r < 4; ++r) {
                int node = base + ms * 16 + hi2 * 4 + r;
                if (node < NN)
                    outp[(size_t)node * D1 + cc] = __float2half(acc[ms][ns][r] + bv);
            }
        }
    }
}

// ---- pass A: LDS-staged coarse partition (TILE=4096, 403 blocks)
__global__ __launch_bounds__(1024) void k_part(
    const int* __restrict__ ei, int* __restrict__ gcnt, unsigned* __restrict__ cstage)
{
    __shared__ int cnt[NCB], loff[NCB + 1], gbasel[NCB], lpos[NCB];
    __shared__ unsigned pay[TILE];
    const int t = threadIdx.x;
    const int ntiles = (EP + TILE - 1) / TILE;
    for (int tile = blockIdx.x; tile < ntiles; tile += gridDim.x) {
        const int tb = tile * TILE;
        const int tc = min(TILE, EP - tb);
        if (t < NCB) cnt[t] = 0;
        __syncthreads();
        unsigned pk0, pk1, pk2, pk3;
#define LOADK(K, PK)                                              \
        {   int i = t + (K) * 1024;                               \
            if (i < tc) {                                         \
                int e = tb + i; int s, d;                         \
                if (e < NE) { s = ei[e]; d = ei[NE + e]; }        \
                else        { s = e - NE; d = s; }                \
                PK = ((unsigned)d << 16) | (unsigned)s;           \
                atomicAdd(&cnt[d >> CBSH], 1);                    \
            } }
        LOADK(0, pk0) LOADK(1, pk1) LOADK(2, pk2) LOADK(3, pk3)
#undef LOADK
        __syncthreads();
        if (t == 0) {
            int run = 0;
            for (int b = 0; b < NCB; ++b) { loff[b] = run; run += cnt[b]; }
            loff[NCB] = run;
        }
        __syncthreads();
        if (t < NCB) {
            gbasel[t] = atomicAdd(&gcnt[t], cnt[t]);
            lpos[t] = loff[t];
        }
        __syncthreads();
#define PLACEK(K, PK)                                             \
        {   int i = t + (K) * 1024;                               \
            if (i < tc) {                                         \
                int cb = (int)(PK >> (16 + CBSH));                \
                int p = atomicAdd(&lpos[cb], 1);                  \
                pay[p] = PK;                                      \
            } }
        PLACEK(0, pk0) PLACEK(1, pk1) PLACEK(2, pk2) PLACEK(3, pk3)
#undef PLACEK
        __syncthreads();
        for (int j = t; j < tc; j += 1024) {
            unsigned v = pay[j];
            int cb = (int)(v >> (16 + CBSH));
            int pos = gbasel[cb] + (j - loff[cb]);
            if (pos < GCAP) cstage[(size_t)cb * GCAP + pos] = v;
        }
        __syncthreads();
    }
}

// ---- tiny scan over coarse buckets
__global__ void k_cscan(const int* __restrict__ gcnt, int* __restrict__ gbase,
                        int* __restrict__ rowst)
{
    if (threadIdx.x == 0) {
        int run = 0;
        for (int b = 0; b < NCB; ++b) { gbase[b] = run; run += min(gcnt[b], GCAP); }
        rowst[NN] = run;
    }
}

// ---- pass B: per coarse bucket: 128-dst LDS hist -> rowst; scatter u16 src
__global__ __launch_bounds__(1024) void k_build2(
    const int* __restrict__ gcnt, const int* __restrict__ gbase,
    const unsigned* __restrict__ cstage,
    int* __restrict__ rowst, unsigned short* __restrict__ csr)
{
    const int b = blockIdx.x;
    const int t = threadIdx.x;
    __shared__ int hist[128], sc[128], curs[128];
    const int cnt = min(gcnt[b], GCAP);
    const int base = gbase[b];
    const int d0 = b << CBSH;
    const int nd = min(128, NN - d0);
    if (t < 128) hist[t] = 0;
    __syncthreads();
    const unsigned* __restrict__ src = cstage + (size_t)b * GCAP;
    for (int i = t; i < cnt; i += 1024)
        atomicAdd(&hist[(src[i] >> 16) & 127], 1);
    __syncthreads();
    if (t < 128) sc[t] = hist[t];
    __syncthreads();
    for (int off = 1; off < 128; off <<= 1) {
        int v = 0;
        if (t < 128 && t >= off) v = sc[t - off];
        __syncthreads();
        if (t < 128) sc[t] += v;
        __syncthreads();
    }
    if (t < 128) {
        int excl = sc[t] - hist[t];
        curs[t] = excl;
        if (t < nd) rowst[d0 + t] = base + excl;
    }
    __syncthreads();
    for (int i = t; i < cnt; i += 1024) {
        unsigned v = src[i];
        int p = atomicAdd(&curs[(v >> 16) & 127], 1);
        csr[base + p] = (unsigned short)(v & 0xFFFFu);
    }
}

// ---- layer-0 fused + gemm1 epilogue; packed-fp16 accumulators; exp2 logits
__global__ __launch_bounds__(256) void k_agg0(
    const int* __restrict__ rowst, const unsigned short* __restrict__ csr,
    const __half* __restrict__ xl0, const __half* __restrict__ xr0,
    const float* __restrict__ att0, const float* __restrict__ bias0,
    const float* __restrict__ Wl1, const float* __restrict__ bl1,
    const float* __restrict__ Wr1, const float* __restrict__ br1,
    float* __restrict__ xl1, float* __restrict__ xr1)
{
    const int d = (blockIdx.x * 256 + threadIdx.x) >> 6;
    const int lane = threadIdx.x & 63;
    if (d >= NN) return;
    const int slot  = lane >> 4;
    const int lane4 = lane & 15;
    const int c0 = lane4 * 8;

    uint4 xrw = *reinterpret_cast<const uint4*>(xr0 + (size_t)d * D1 + c0);
    H2U xr01, xr23, xr45, xr67;
    xr01.u = xrw.x; xr23.u = xrw.y; xr45.u = xrw.z; xr67.u = xrw.w;
    float4 atf0 = *reinterpret_cast<const float4*>(att0 + c0);
    float4 atf1 = *reinterpret_cast<const float4*>(att0 + c0 + 4);
    H2U at01, at23, at45, at67;
    at01.h = __floats2half2_rn(atf0.x * LOG2E, atf0.y * LOG2E);
    at23.h = __floats2half2_rn(atf0.z * LOG2E, atf0.w * LOG2E);
    at45.h = __floats2half2_rn(atf1.x * LOG2E, atf1.y * LOG2E);
    at67.h = __floats2half2_rn(atf1.z * LOG2E, atf1.w * LOG2E);
    const _Float16 kneg = (_Float16)NEG;
    const h2v k2 = { kneg, kneg };

    const int rs = rowst[d];
    const int cnt = rowst[d + 1] - rs;
    h2v a01 = {(_Float16)0.f, (_Float16)0.f};
    h2v a23 = a01, a45 = a01, a67 = a01;
    float wsum = 0.f;

#define EDGE(W, VALID)                                                      \
    {   H2U x01, x23, x45, x67;                                             \
        x01.u = (W).x; x23.u = (W).y; x45.u = (W).z; x67.u = (W).w;         \
        h2v s01 = x01.v + xr01.v, s23 = x23.v + xr23.v;                     \
        h2v s45 = x45.v + xr45.v, s67 = x67.v + xr67.v;                     \
        h2v l01 = __builtin_elementwise_max(s01, s01 * k2);                 \
        h2v l23 = __builtin_elementwise_max(s23, s23 * k2);                 \
        h2v l45 = __builtin_elementwise_max(s45, s45 * k2);                 \
        h2v l67 = __builtin_elementwise_max(s67, s67 * k2);                 \
        float p = __builtin_amdgcn_fdot2(l01, at01.v,                       \
                  __builtin_amdgcn_fdot2(l23, at23.v,                       \
                  __builtin_amdgcn_fdot2(l45, at45.v,                       \
                  __builtin_amdgcn_fdot2(l67, at67.v, 0.f, false),          \
                  false), false), false);                                   \
        p += __shfl_xor(p, 1);                                              \
        p += __shfl_xor(p, 2);                                              \
        float wgt = (VALID) ? exp2f(p) : 0.f;                               \
        _Float16 wh = (_Float16)wgt;                                        \
        h2v w2 = { wh, wh };                                                \
        a01 = __builtin_elementwise_fma(w2, x01.v, a01);                    \
        a23 = __builtin_elementwise_fma(w2, x23.v, a23);                    \
        a45 = __builtin_elementwise_fma(w2, x45.v, a45);                    \
        a67 = __builtin_elementwise_fma(w2, x67.v, a67);                    \
        wsum += wgt;                                                        \
    }

    int i = 0;
    for (; i + 8 <= cnt; i += 8) {
        int s0 = csr[rs + i + slot];
        int s1 = csr[rs + i + 4 + slot];
        uint4 w0 = *reinterpret_cast<const uint4*>(xl0 + (size_t)s0 * D1 + c0);
        uint4 w1 = *reinterpret_cast<const uint4*>(xl0 + (size_t)s1 * D1 + c0);
        EDGE(w0, true);
        EDGE(w1, true);
    }
    for (; i < cnt; i += 4) {
        int e = i + slot;
        bool valid = (e < cnt);
        int s = csr[rs + (valid ? e : 0)];
        uint4 w = *reinterpret_cast<const uint4*>(xl0 + (size_t)s * D1 + c0);
        EDGE(w, valid);
    }
#undef EDGE

    H2U u01, u23, u45, u67;
    u01.v = a01; u23.v = a23; u45.v = a45; u67.v = a67;
    float2 f01 = __half22float2(u01.h), f23 = __half22float2(u23.h);
    float2 f45 = __half22float2(u45.h), f67 = __half22float2(u67.h);
    float acc0 = f01.x, acc1 = f01.y, acc2 = f23.x, acc3 = f23.y;
    float acc4 = f45.x, acc5 = f45.y, acc6 = f67.x, acc7 = f67.y;

#define COMB(V) V += __shfl_xor(V, 16); V += __shfl_xor(V, 32);
    COMB(acc0) COMB(acc1) COMB(acc2) COMB(acc3)
    COMB(acc4) COMB(acc5) COMB(acc6) COMB(acc7)
    COMB(wsum)
#undef COMB

    if (slot == 0) {
        float r = 1.f / (wsum + 1e-16f);
        float4 b0 = *reinterpret_cast<const float4*>(bias0 + c0);
        float4 b1 = *reinterpret_cast<const float4*>(bias0 + c0 + 4);
        float h[8];
        h[0] = fmaxf(acc0 * r + b0.x, 0.f);
        h[1] = fmaxf(acc1 * r + b0.y, 0.f);
        h[2] = fmaxf(acc2 * r + b0.z, 0.f);
        h[3] = fmaxf(acc3 * r + b0.w, 0.f);
        h[4] = fmaxf(acc4 * r + b1.x, 0.f);
        h[5] = fmaxf(acc5 * r + b1.y, 0.f);
        h[6] = fmaxf(acc6 * r + b1.z, 0.f);
        h[7] = fmaxf(acc7 * r + b1.w, 0.f);
        float pl0 = 0.f, pl1 = 0.f, pr0 = 0.f, pr1 = 0.f;
#pragma unroll
        for (int j = 0; j < 8; ++j) {
            float2 wl = *reinterpret_cast<const float2*>(Wl1 + (c0 + j) * 2);
            float2 wr = *reinterpret_cast<const float2*>(Wr1 + (c0 + j) * 2);
            pl0 += h[j] * wl.x; pl1 += h[j] * wl.y;
            pr0 += h[j] * wr.x; pr1 += h[j] * wr.y;
        }
#pragma unroll
        for (int ofs = 1; ofs < 16; ofs <<= 1) {
            pl0 += __shfl_xor(pl0, ofs);
            pl1 += __shfl_xor(pl1, ofs);
            pr0 += __shfl_xor(pr0, ofs);
            pr1 += __shfl_xor(pr1, ofs);
        }
        if (lane4 == 0) {
            *reinterpret_cast<float2*>(xl1 + (size_t)d * 2) =
                make_float2(pl0 + bl1[0], pl1 + bl1[1]);
            *reinterpret_cast<float2*>(xr1 + (size_t)d * 2) =
                make_float2(pr0 + br1[0], pr1 + br1[1]);
        }
    }
}

// ---- layer-1 fused: 4 lanes per dst; strided edges + 2-step shuffle combine
__global__ __launch_bounds__(256) void k_layer1(
    const int* __restrict__ rowst, const unsigned short* __restrict__ csr,
    const float* __restrict__ xl1, const float* __restrict__ xr1,
    const float* __restrict__ att1, const float* __restrict__ bias1,
    float* __restrict__ out)
{
    const int d = (blockIdx.x * 256 + threadIdx.x) >> 2;
    const int sub = threadIdx.x & 3;
    if (d >= NN) return;
    float2 xr = *reinterpret_cast<const float2*>(xr1 + (size_t)d * 2);
    float A0 = att1[0], A1 = att1[1];
    const int rs = rowst[d], re = rowst[d + 1];
    float sum = 0.f, a0 = 0.f, a1 = 0.f;
    for (int i = rs + sub; i < re; i += 4) {
        int s = csr[i];
        float2 xs = *reinterpret_cast<const float2*>(xl1 + (size_t)s * 2);
        float wgt = __expf(lrelu(xs.x + xr.x) * A0 + lrelu(xs.y + xr.y) * A1);
        sum += wgt;
        a0 += wgt * xs.x;
        a1 += wgt * xs.y;
    }
    sum += __shfl_xor(sum, 1); sum += __shfl_xor(sum, 2);
    a0  += __shfl_xor(a0, 1);  a0  += __shfl_xor(a0, 2);
    a1  += __shfl_xor(a1, 1);  a1  += __shfl_xor(a1, 2);
    if (sub == 0) {
        float r = 1.f / (sum + 1e-16f);
        out[(size_t)d * 2]     = a0 * r + bias1[0];
        out[(size_t)d * 2 + 1] = a1 * r + bias1[1];
    }
}

extern "C" void kernel_launch(void* const* d_in, const int* in_sizes, int n_in,
                              void* d_out, int out_size, void* d_ws, size_t ws_size,
                              hipStream_t stream)
{
    const float* x     = (const float*)d_in[0];
    const int*   ei    = (const int*)d_in[1];
    const int*   ts    = (const int*)d_in[2];
    const float* Wt    = (const float*)d_in[3];
    const float* Wl0   = (const float*)d_in[4];
    const float* bl0   = (const float*)d_in[5];
    const float* Wr0   = (const float*)d_in[6];
    const float* br0   = (const float*)d_in[7];
    const float* att0  = (const float*)d_in[8];
    const float* bias0 = (const float*)d_in[9];
    const float* Wl1   = (const float*)d_in[10];
    const float* bl1   = (const float*)d_in[11];
    const float* Wr1   = (const float*)d_in[12];
    const float* br1   = (const float*)d_in[13];
    const float* att1  = (const float*)d_in[14];
    const float* bias1 = (const float*)d_in[15];
    float* out = (float*)d_out;

    char* wsp = (char*)d_ws;
    size_t off = 0;
    auto alloc = [&](size_t bytes) -> void* {
        void* p = wsp + off;
        off += (bytes + 255) & ~(size_t)255;
        return p;
    };
    __half* xl0  = (__half*)alloc((size_t)NN * D1 * 2);
    __half* xr0  = (__half*)alloc((size_t)NN * D1 * 2);
    float* xl1   = (float*)alloc((size_t)NN * 2 * 4);
    float* xr1   = (float*)alloc((size_t)NN * 2 * 4);
    int* rowst   = (int*)alloc((size_t)(NN + 1) * 4);
    unsigned short* csr = (unsigned short*)alloc((size_t)EP * 2);
    int* gcnt        = (int*)alloc((size_t)NCB * 4);
    int* gbase       = (int*)alloc((size_t)NCB * 4);
    unsigned* cstage = (unsigned*)alloc((size_t)NCB * GCAP * 4);
    __half* Btg      = (__half*)alloc((size_t)256 * INDIM * 2);
    float* bcat      = (float*)alloc((size_t)256 * 4);

    k_wcast<<<(256 * INDIM + 255) / 256, 256, 0, stream>>>(Wl0, Wr0, bl0, br0, Btg, bcat);
    k_gemm0m<<<(NN + MT - 1) / MT, 256, 0, stream>>>(x, ts, Wt, Btg, bcat, xl0, xr0);

    (void)hipMemsetAsync(gcnt, 0, (size_t)NCB * 4, stream);
    const int ntiles = (EP + TILE - 1) / TILE;
    k_part<<<ntiles, 1024, 0, stream>>>(ei, gcnt, cstage);
    k_cscan<<<1, 64, 0, stream>>>(gcnt, gbase, rowst);
    k_build2<<<NCB, 1024, 0, stream>>>(gcnt, gbase, cstage, rowst, csr);

    k_agg0<<<(NN + 3) / 4, 256, 0, stream>>>(rowst, csr, xl0, xr0, att0, bias0,
                                             Wl1, bl1, Wr1, br1, xl1, xr1);
    k_layer1<<<(NN * 4 + 255) / 256, 256, 0, stream>>>(rowst, csr, xl1, xr1, att1, bias1, out);
}

// Round 25
// 139.305 us; speedup vs baseline: 1.0908x; 1.0908x over previous
//
#include <hip/hip_runtime.h>
#include <hip/hip_fp16.h>

#define NN 50000
#define NE 1600000
#define EP (NE + NN)
#define INC 64
#define TDIM 32
#define INDIM 96
#define D1 128
#define NEG 0.2f
#define LOG2E 1.44269504f

#define CBSH 8
#define NCB 196               // ceil(NN / 256)
#define GCAP 9600             // mean 8418 + 12 sigma
#define TILE 8192

#define MT 64                 // gemm0 M-tile rows per block
#define KP 104                // padded K stride (208B rows, 16B aligned)

typedef _Float16 h2v __attribute__((ext_vector_type(2)));
typedef _Float16 f16x8 __attribute__((ext_vector_type(8)));
typedef float f32x4 __attribute__((ext_vector_type(4)));
union H2U { unsigned u; __half2 h; h2v v; };

__device__ __forceinline__ float lrelu(float v) { return v > 0.f ? v : NEG * v; }

// ---- pack Wl|Wr into transposed fp16 B [256][96] + bias concat [256]
__global__ __launch_bounds__(256) void k_wcast(
    const float* __restrict__ Wl, const float* __restrict__ Wr,
    const float* __restrict__ bl, const float* __restrict__ br,
    __half* __restrict__ Btg, float* __restrict__ bcat)
{
    int idx = blockIdx.x * 256 + threadIdx.x;
    if (idx < 256) bcat[idx] = (idx < 128) ? bl[idx] : br[idx - 128];
    if (idx >= 256 * INDIM) return;
    int c = idx / INDIM, k = idx - c * INDIM;
    float v = (c < 128) ? Wl[k * D1 + c] : Wr[k * D1 + (c - 128)];
    Btg[idx] = __float2half(v);
}

// ---- GEMM0 via MFMA: B prefetched to registers; A staged in LDS (13KB)
__global__ __launch_bounds__(256) void k_gemm0m(
    const float* __restrict__ x, const int* __restrict__ ts,
    const float* __restrict__ Wt,
    const __half* __restrict__ Btg, const float* __restrict__ bcat,
    __half* __restrict__ xl0, __half* __restrict__ xr0)
{
    __shared__ _Float16 As[MT][KP];
    const int t = threadIdx.x;
    const int base = blockIdx.x * MT;
    const float4* __restrict__ x4  = reinterpret_cast<const float4*>(x);
    const float4* __restrict__ wt4 = reinterpret_cast<const float4*>(Wt);

    const int lane = t & 63;
    const int w = t >> 6;
    const int lo4 = lane & 15;
    const int hi2 = lane >> 4;

    f16x8 bfr[3][4];
#pragma unroll
    for (int ks = 0; ks < 3; ++ks)
#pragma unroll
        for (int ns = 0; ns < 4; ++ns)
            bfr[ks][ns] = *reinterpret_cast<const f16x8*>(
                Btg + (size_t)(w * 64 + ns * 16 + lo4) * INDIM + ks * 32 + hi2 * 8);

    float4 av0, av1, av2, av3, av4, av5;
#define LOADA(J, AV)                                                   \
    {   int c = t + (J) * 256;                                         \
        int m = c / 24, q = c - m * 24;                                \
        int n = base + m;                                              \
        if (n < NN)                                                    \
            AV = (q < 16) ? x4[(size_t)n * 16 + q]                     \
                          : wt4[(size_t)ts[n] * 8 + (q - 16)];         \
        else AV = make_float4(0.f, 0.f, 0.f, 0.f);                     \
    }
    LOADA(0, av0) LOADA(1, av1) LOADA(2, av2)
    LOADA(3, av3) LOADA(4, av4) LOADA(5, av5)
#undef LOADA
#define WRITEA(J, AV)                                                  \
    {   int c = t + (J) * 256;                                         \
        int m = c / 24, q = c - m * 24;                                \
        h2v p01 = { (_Float16)AV.x, (_Float16)AV.y };                  \
        h2v p23 = { (_Float16)AV.z, (_Float16)AV.w };                  \
        *reinterpret_cast<h2v*>(&As[m][q * 4])     = p01;              \
        *reinterpret_cast<h2v*>(&As[m][q * 4 + 2]) = p23;              \
    }
    WRITEA(0, av0) WRITEA(1, av1) WRITEA(2, av2)
    WRITEA(3, av3) WRITEA(4, av4) WRITEA(5, av5)
#undef WRITEA
    __syncthreads();

    f32x4 acc[4][4] = {};
#pragma unroll
    for (int ks = 0; ks < 3; ++ks) {
        const int kb = ks * 32 + hi2 * 8;
        f16x8 a[4];
#pragma unroll
        for (int ms = 0; ms < 4; ++ms)
            a[ms] = *reinterpret_cast<const f16x8*>(&As[ms * 16 + lo4][kb]);
#pragma unroll
        for (int ms = 0; ms < 4; ++ms)
#pragma unroll
            for (int ns = 0; ns < 4; ++ns)
                acc[ms][ns] = __builtin_amdgcn_mfma_f32_16x16x32_f16(
                    a[ms], bfr[ks][ns], acc[ms][ns], 0, 0, 0);
    }

#pragma unroll
    for (int ms = 0; ms < 4; ++ms) {
#pragma unroll
        for (int ns = 0; ns < 4; ++ns) {
            int col = w * 64 + ns * 16 + lo4;
            float bv = bcat[col];
            __half* outp = (col & 128) ? xr0 : xl0;
            int cc = col & 127;
#pragma unroll
            for (int r = 0; r < 4; ++r) {
                int node = base + ms * 16 + hi2 * 4 + r;
                if (node < NN)
                    outp[(size_t)node * D1 + cc] = __float2half(acc[ms][ns][r] + bv);
            }
        }
    }
}

// ---- pass A: LDS-staged coarse partition (R22 config: TILE=8192)
__global__ __launch_bounds__(1024) void k_part(
    const int* __restrict__ ei, int* __restrict__ gcnt, unsigned* __restrict__ cstage)
{
    __shared__ int cnt[NCB], loff[NCB + 1], gbasel[NCB], lpos[NCB];
    __shared__ unsigned pay[TILE];
    const int t = threadIdx.x;
    const int ntiles = (EP + TILE - 1) / TILE;
    for (int tile = blockIdx.x; tile < ntiles; tile += gridDim.x) {
        const int tb = tile * TILE;
        const int tc = min(TILE, EP - tb);
        if (t < NCB) cnt[t] = 0;
        __syncthreads();
        unsigned pk0, pk1, pk2, pk3, pk4, pk5, pk6, pk7;
#define LOADK(K, PK)                                              \
        {   int i = t + (K) * 1024;                               \
            if (i < tc) {                                         \
                int e = tb + i; int s, d;                         \
                if (e < NE) { s = ei[e]; d = ei[NE + e]; }        \
                else        { s = e - NE; d = s; }                \
                PK = ((unsigned)d << 16) | (unsigned)s;           \
                atomicAdd(&cnt[d >> CBSH], 1);                    \
            } }
        LOADK(0, pk0) LOADK(1, pk1) LOADK(2, pk2) LOADK(3, pk3)
        LOADK(4, pk4) LOADK(5, pk5) LOADK(6, pk6) LOADK(7, pk7)
#undef LOADK
        __syncthreads();
        if (t == 0) {
            int run = 0;
            for (int b = 0; b < NCB; ++b) { loff[b] = run; run += cnt[b]; }
            loff[NCB] = run;
        }
        __syncthreads();
        if (t < NCB) {
            gbasel[t] = atomicAdd(&gcnt[t], cnt[t]);
            lpos[t] = loff[t];
        }
        __syncthreads();
#define PLACEK(K, PK)                                             \
        {   int i = t + (K) * 1024;                               \
            if (i < tc) {                                         \
                int cb = (int)(PK >> (16 + CBSH));                \
                int p = atomicAdd(&lpos[cb], 1);                  \
                pay[p] = PK;                                      \
            } }
        PLACEK(0, pk0) PLACEK(1, pk1) PLACEK(2, pk2) PLACEK(3, pk3)
        PLACEK(4, pk4) PLACEK(5, pk5) PLACEK(6, pk6) PLACEK(7, pk7)
#undef PLACEK
        __syncthreads();
        for (int j = t; j < tc; j += 1024) {
            unsigned v = pay[j];
            int cb = (int)(v >> (16 + CBSH));
            int pos = gbasel[cb] + (j - loff[cb]);
            if (pos < GCAP) cstage[(size_t)cb * GCAP + pos] = v;
        }
        __syncthreads();
    }
}

// ---- tiny scan over coarse buckets
__global__ void k_cscan(const int* __restrict__ gcnt, int* __restrict__ gbase,
                        int* __restrict__ rowst)
{
    if (threadIdx.x == 0) {
        int run = 0;
        for (int b = 0; b < NCB; ++b) { gbase[b] = run; run += min(gcnt[b], GCAP); }
        rowst[NN] = run;
    }
}

// ---- pass B: per coarse bucket: 256-dst LDS hist -> rowst; scatter u16 src
__global__ __launch_bounds__(1024) void k_build2(
    const int* __restrict__ gcnt, const int* __restrict__ gbase,
    const unsigned* __restrict__ cstage,
    int* __restrict__ rowst, unsigned short* __restrict__ csr)
{
    const int b = blockIdx.x;
    const int t = threadIdx.x;
    __shared__ int hist[256], sc[256], curs[256];
    const int cnt = min(gcnt[b], GCAP);
    const int base = gbase[b];
    const int d0 = b << CBSH;
    const int nd = min(256, NN - d0);
    if (t < 256) hist[t] = 0;
    __syncthreads();
    const unsigned* __restrict__ src = cstage + (size_t)b * GCAP;
    for (int i = t; i < cnt; i += 1024)
        atomicAdd(&hist[(src[i] >> 16) & 255], 1);
    __syncthreads();
    if (t < 256) sc[t] = hist[t];
    __syncthreads();
    for (int off = 1; off < 256; off <<= 1) {
        int v = 0;
        if (t < 256 && t >= off) v = sc[t - off];
        __syncthreads();
        if (t < 256) sc[t] += v;
        __syncthreads();
    }
    if (t < 256) {
        int excl = sc[t] - hist[t];
        curs[t] = excl;
        if (t < nd) rowst[d0 + t] = base + excl;
    }
    __syncthreads();
    for (int i = t; i < cnt; i += 1024) {
        unsigned v = src[i];
        int p = atomicAdd(&curs[(v >> 16) & 255], 1);
        csr[base + p] = (unsigned short)(v & 0xFFFFu);
    }
}

// ---- layer-0 fused + gemm1 epilogue; pk-fp16 acc; exp2; pipelined index loads
__global__ __launch_bounds__(256) void k_agg0(
    const int* __restrict__ rowst, const unsigned short* __restrict__ csr,
    const __half* __restrict__ xl0, const __half* __restrict__ xr0,
    const float* __restrict__ att0, const float* __restrict__ bias0,
    const float* __restrict__ Wl1, const float* __restrict__ bl1,
    const float* __restrict__ Wr1, const float* __restrict__ br1,
    float* __restrict__ xl1, float* __restrict__ xr1)
{
    const int d = (blockIdx.x * 256 + threadIdx.x) >> 6;
    const int lane = threadIdx.x & 63;
    if (d >= NN) return;
    const int slot  = lane >> 4;
    const int lane4 = lane & 15;
    const int c0 = lane4 * 8;

    uint4 xrw = *reinterpret_cast<const uint4*>(xr0 + (size_t)d * D1 + c0);
    H2U xr01, xr23, xr45, xr67;
    xr01.u = xrw.x; xr23.u = xrw.y; xr45.u = xrw.z; xr67.u = xrw.w;
    float4 atf0 = *reinterpret_cast<const float4*>(att0 + c0);
    float4 atf1 = *reinterpret_cast<const float4*>(att0 + c0 + 4);
    H2U at01, at23, at45, at67;
    at01.h = __floats2half2_rn(atf0.x * LOG2E, atf0.y * LOG2E);
    at23.h = __floats2half2_rn(atf0.z * LOG2E, atf0.w * LOG2E);
    at45.h = __floats2half2_rn(atf1.x * LOG2E, atf1.y * LOG2E);
    at67.h = __floats2half2_rn(atf1.z * LOG2E, atf1.w * LOG2E);
    const _Float16 kneg = (_Float16)NEG;
    const h2v k2 = { kneg, kneg };

    const int rs = rowst[d];
    const int cnt = rowst[d + 1] - rs;
    h2v a01 = {(_Float16)0.f, (_Float16)0.f};
    h2v a23 = a01, a45 = a01, a67 = a01;
    float wsum = 0.f;

#define EDGE(W, VALID)                                                      \
    {   H2U x01, x23, x45, x67;                                             \
        x01.u = (W).x; x23.u = (W).y; x45.u = (W).z; x67.u = (W).w;         \
        h2v s01 = x01.v + xr01.v, s23 = x23.v + xr23.v;                     \
        h2v s45 = x45.v + xr45.v, s67 = x67.v + xr67.v;                     \
        h2v l01 = __builtin_elementwise_max(s01, s01 * k2);                 \
        h2v l23 = __builtin_elementwise_max(s23, s23 * k2);                 \
        h2v l45 = __builtin_elementwise_max(s45, s45 * k2);                 \
        h2v l67 = __builtin_elementwise_max(s67, s67 * k2);                 \
        float p = __builtin_amdgcn_fdot2(l01, at01.v,                       \
                  __builtin_amdgcn_fdot2(l23, at23.v,                       \
                  __builtin_amdgcn_fdot2(l45, at45.v,                       \
                  __builtin_amdgcn_fdot2(l67, at67.v, 0.f, false),          \
                  false), false), false);                                   \
        p += __shfl_xor(p, 1);                                              \
        p += __shfl_xor(p, 2);                                              \
        float wgt = (VALID) ? exp2f(p) : 0.f;                               \
        _Float16 wh = (_Float16)wgt;                                        \
        h2v w2 = { wh, wh };                                                \
        a01 = __builtin_elementwise_fma(w2, x01.v, a01);                    \
        a23 = __builtin_elementwise_fma(w2, x23.v, a23);                    \
        a45 = __builtin_elementwise_fma(w2, x45.v, a45);                    \
        a67 = __builtin_elementwise_fma(w2, x67.v, a67);                    \
        wsum += wgt;                                                        \
    }

    int i = 0;
    if (cnt >= 8) {
        int s0 = csr[rs + slot];
        int s1 = csr[rs + 4 + slot];
        for (; i + 8 <= cnt; i += 8) {
            uint4 w0 = *reinterpret_cast<const uint4*>(xl0 + (size_t)s0 * D1 + c0);
            uint4 w1 = *reinterpret_cast<const uint4*>(xl0 + (size_t)s1 * D1 + c0);
            if (i + 16 <= cnt) {                 // prefetch next iteration's indices
                s0 = csr[rs + i + 8 + slot];
                s1 = csr[rs + i + 12 + slot];
            }
            EDGE(w0, true);
            EDGE(w1, true);
        }
    }
    for (; i < cnt; i += 4) {
        int e = i + slot;
        bool valid = (e < cnt);
        int s = csr[rs + (valid ? e : 0)];
        uint4 w = *reinterpret_cast<const uint4*>(xl0 + (size_t)s * D1 + c0);
        EDGE(w, valid);
    }
#undef EDGE

    H2U u01, u23, u45, u67;
    u01.v = a01; u23.v = a23; u45.v = a45; u67.v = a67;
    float2 f01 = __half22float2(u01.h), f23 = __half22float2(u23.h);
    float2 f45 = __half22float2(u45.h), f67 = __half22float2(u67.h);
    float acc0 = f01.x, acc1 = f01.y, acc2 = f23.x, acc3 = f23.y;
    float acc4 = f45.x, acc5 = f45.y, acc6 = f67.x, acc7 = f67.y;

#define COMB(V) V += __shfl_xor(V, 16); V += __shfl_xor(V, 32);
    COMB(acc0) COMB(acc1) COMB(acc2) COMB(acc3)
    COMB(acc4) COMB(acc5) COMB(acc6) COMB(acc7)
    COMB(wsum)
#undef COMB

    if (slot == 0) {
        float r = 1.f / (wsum + 1e-16f);
        float4 b0 = *reinterpret_cast<const float4*>(bias0 + c0);
        float4 b1 = *reinterpret_cast<const float4*>(bias0 + c0 + 4);
        float h[8];
        h[0] = fmaxf(acc0 * r + b0.x, 0.f);
        h[1] = fmaxf(acc1 * r + b0.y, 0.f);
        h[2] = fmaxf(acc2 * r + b0.z, 0.f);
        h[3] = fmaxf(acc3 * r + b0.w, 0.f);
        h[4] = fmaxf(acc4 * r + b1.x, 0.f);
        h[5] = fmaxf(acc5 * r + b1.y, 0.f);
        h[6] = fmaxf(acc6 * r + b1.z, 0.f);
        h[7] = fmaxf(acc7 * r + b1.w, 0.f);
        float pl0 = 0.f, pl1 = 0.f, pr0 = 0.f, pr1 = 0.f;
#pragma unroll
        for (int j = 0; j < 8; ++j) {
            float2 wl = *reinterpret_cast<const float2*>(Wl1 + (c0 + j) * 2);
            float2 wr = *reinterpret_cast<const float2*>(Wr1 + (c0 + j) * 2);
            pl0 += h[j] * wl.x; pl1 += h[j] * wl.y;
            pr0 += h[j] * wr.x; pr1 += h[j] * wr.y;
        }
#pragma unroll
        for (int ofs = 1; ofs < 16; ofs <<= 1) {
            pl0 += __shfl_xor(pl0, ofs);
            pl1 += __shfl_xor(pl1, ofs);
            pr0 += __shfl_xor(pr0, ofs);
            pr1 += __shfl_xor(pr1, ofs);
        }
        if (lane4 == 0) {
            *reinterpret_cast<float2*>(xl1 + (size_t)d * 2) =
                make_float2(pl0 + bl1[0], pl1 + bl1[1]);
            *reinterpret_cast<float2*>(xr1 + (size_t)d * 2) =
                make_float2(pr0 + br1[0], pr1 + br1[1]);
        }
    }
}

// ---- layer-1 fused: 4 lanes per dst; strided edges + 2-step shuffle combine
__global__ __launch_bounds__(256) void k_layer1(
    const int* __restrict__ rowst, const unsigned short* __restrict__ csr,
    const float* __restrict__ xl1, const float* __restrict__ xr1,
    const float* __restrict__ att1, const float* __restrict__ bias1,
    float* __restrict__ out)
{
    const int d = (blockIdx.x * 256 + threadIdx.x) >> 2;
    const int sub = threadIdx.x & 3;
    if (d >= NN) return;
    float2 xr = *reinterpret_cast<const float2*>(xr1 + (size_t)d * 2);
    float A0 = att1[0], A1 = att1[1];
    const int rs = rowst[d], re = rowst[d + 1];
    float sum = 0.f, a0 = 0.f, a1 = 0.f;
    for (int i = rs + sub; i < re; i += 4) {
        int s = csr[i];
        float2 xs = *reinterpret_cast<const float2*>(xl1 + (size_t)s * 2);
        float wgt = __expf(lrelu(xs.x + xr.x) * A0 + lrelu(xs.y + xr.y) * A1);
        sum += wgt;
        a0 += wgt * xs.x;
        a1 += wgt * xs.y;
    }
    sum += __shfl_xor(sum, 1); sum += __shfl_xor(sum, 2);
    a0  += __shfl_xor(a0, 1);  a0  += __shfl_xor(a0, 2);
    a1  += __shfl_xor(a1, 1);  a1  += __shfl_xor(a1, 2);
    if (sub == 0) {
        float r = 1.f / (sum + 1e-16f);
        out[(size_t)d * 2]     = a0 * r + bias1[0];
        out[(size_t)d * 2 + 1] = a1 * r + bias1[1];
    }
}

extern "C" void kernel_launch(void* const* d_in, const int* in_sizes, int n_in,
                              void* d_out, int out_size, void* d_ws, size_t ws_size,
                              hipStream_t stream)
{
    const float* x     = (const float*)d_in[0];
    const int*   ei    = (const int*)d_in[1];
    const int*   ts    = (const int*)d_in[2];
    const float* Wt    = (const float*)d_in[3];
    const float* Wl0   = (const float*)d_in[4];
    const float* bl0   = (const float*)d_in[5];
    const float* Wr0   = (const float*)d_in[6];
    const float* br0   = (const float*)d_in[7];
    const float* att0  = (const float*)d_in[8];
    const float* bias0 = (const float*)d_in[9];
    const float* Wl1   = (const float*)d_in[10];
    const float* bl1   = (const float*)d_in[11];
    const float* Wr1   = (const float*)d_in[12];
    const float* br1   = (const float*)d_in[13];
    const float* att1  = (const float*)d_in[14];
    const float* bias1 = (const float*)d_in[15];
    float* out = (float*)d_out;

    char* wsp = (char*)d_ws;
    size_t off = 0;
    auto alloc = [&](size_t bytes) -> void* {
        void* p = wsp + off;
        off += (bytes + 255) & ~(size_t)255;
        return p;
    };
    __half* xl0  = (__half*)alloc((size_t)NN * D1 * 2);
    __half* xr0  = (__half*)alloc((size_t)NN * D1 * 2);
    float* xl1   = (float*)alloc((size_t)NN * 2 * 4);
    float* xr1   = (float*)alloc((size_t)NN * 2 * 4);
    int* rowst   = (int*)alloc((size_t)(NN + 1) * 4);
    unsigned short* csr = (unsigned short*)alloc((size_t)EP * 2);
    int* gcnt        = (int*)alloc((size_t)NCB * 4);
    int* gbase       = (int*)alloc((size_t)NCB * 4);
    unsigned* cstage = (unsigned*)alloc((size_t)NCB * GCAP * 4);
    __half* Btg      = (__half*)alloc((size_t)256 * INDIM * 2);
    float* bcat      = (float*)alloc((size_t)256 * 4);

    k_wcast<<<(256 * INDIM + 255) / 256, 256, 0, stream>>>(Wl0, Wr0, bl0, br0, Btg, bcat);
    k_gemm0m<<<(NN + MT - 1) / MT, 256, 0, stream>>>(x, ts, Wt, Btg, bcat, xl0, xr0);

    (void)hipMemsetAsync(gcnt, 0, (size_t)NCB * 4, stream);
    const int ntiles = (EP + TILE - 1) / TILE;
    k_part<<<ntiles, 1024, 0, stream>>>(ei, gcnt, cstage);
    k_cscan<<<1, 64, 0, stream>>>(gcnt, gbase, rowst);
    k_build2<<<NCB, 1024, 0, stream>>>(gcnt, gbase, cstage, rowst, csr);

    k_agg0<<<(NN + 3) / 4, 256, 0, stream>>>(rowst, csr, xl0, xr0, att0, bias0,
                                             Wl1, bl1, Wr1, br1, xl1, xr1);
    k_layer1<<<(NN * 4 + 255) / 256, 256, 0, stream>>>(rowst, csr, xl1, xr1, att1, bias1, out);
}

// Round 26
// 133.475 us; speedup vs baseline: 1.1384x; 1.0437x over previous
//
#include <hip/hip_runtime.h>
#include <hip/hip_fp16.h>

#define NN 50000
#define NE 1600000
#define EP (NE + NN)
#define INC 64
#define TDIM 32
#define INDIM 96
#define D1 128
#define NEG 0.2f
#define LOG2E 1.44269504f

#define CBSH 8
#define NCB 196               // ceil(NN / 256)
#define GCAP 9600             // mean 8418 + 12 sigma
#define PTILE 2048            // part tile (256 threads x 8)

#define MT 64                 // gemm0 M-tile rows per block
#define KP 104                // padded K stride (208B rows, 16B aligned)
#define NGEMM ((NN + MT - 1) / MT)            // 782
#define NPTILES ((EP + PTILE - 1) / PTILE)    // 806

typedef _Float16 h2v __attribute__((ext_vector_type(2)));
typedef _Float16 f16x8 __attribute__((ext_vector_type(8)));
typedef float f32x4 __attribute__((ext_vector_type(4)));
union H2U { unsigned u; __half2 h; h2v v; };

__device__ __forceinline__ float lrelu(float v) { return v > 0.f ? v : NEG * v; }

// ---- pack Wl|Wr into transposed fp16 B [256][96] + bias concat [256]
__global__ __launch_bounds__(256) void k_wcast(
    const float* __restrict__ Wl, const float* __restrict__ Wr,
    const float* __restrict__ bl, const float* __restrict__ br,
    __half* __restrict__ Btg, float* __restrict__ bcat)
{
    int idx = blockIdx.x * 256 + threadIdx.x;
    if (idx < 256) bcat[idx] = (idx < 128) ? bl[idx] : br[idx - 128];
    if (idx >= 256 * INDIM) return;
    int c = idx / INDIM, k = idx - c * INDIM;
    float v = (c < 128) ? Wl[k * D1 + c] : Wr[k * D1 + (c - 128)];
    Btg[idx] = __float2half(v);
}

// ---- fused dispatch: even blocks = gemm0m (MFMA), odd blocks = edge partition
__global__ __launch_bounds__(256) void k_g0p(
    const float* __restrict__ x, const int* __restrict__ ts,
    const float* __restrict__ Wt,
    const __half* __restrict__ Btg, const float* __restrict__ bcat,
    __half* __restrict__ xl0, __half* __restrict__ xr0,
    const int* __restrict__ ei, int* __restrict__ gcnt,
    unsigned* __restrict__ cstage)
{
    __shared__ union SH {
        _Float16 As[MT][KP];
        struct {
            int cnt[NCB], loff[NCB + 1], gbasel[NCB], lpos[NCB];
            unsigned pay[PTILE];
        } p;
    } sh;
    const int t = threadIdx.x;
    const int half = blockIdx.x >> 1;

    if ((blockIdx.x & 1) == 0) {
        // ================= gemm0m branch =================
        if (half >= NGEMM) return;
        const int base = half * MT;
        const float4* __restrict__ x4  = reinterpret_cast<const float4*>(x);
        const float4* __restrict__ wt4 = reinterpret_cast<const float4*>(Wt);

        const int lane = t & 63;
        const int w = t >> 6;
        const int lo4 = lane & 15;
        const int hi2 = lane >> 4;

        f16x8 bfr[3][4];
#pragma unroll
        for (int ks = 0; ks < 3; ++ks)
#pragma unroll
            for (int ns = 0; ns < 4; ++ns)
                bfr[ks][ns] = *reinterpret_cast<const f16x8*>(
                    Btg + (size_t)(w * 64 + ns * 16 + lo4) * INDIM + ks * 32 + hi2 * 8);

        float4 av0, av1, av2, av3, av4, av5;
#define LOADA(J, AV)                                                   \
        {   int c = t + (J) * 256;                                     \
            int m = c / 24, q = c - m * 24;                            \
            int n = base + m;                                          \
            if (n < NN)                                                \
                AV = (q < 16) ? x4[(size_t)n * 16 + q]                 \
                              : wt4[(size_t)ts[n] * 8 + (q - 16)];     \
            else AV = make_float4(0.f, 0.f, 0.f, 0.f);                 \
        }
        LOADA(0, av0) LOADA(1, av1) LOADA(2, av2)
        LOADA(3, av3) LOADA(4, av4) LOADA(5, av5)
#undef LOADA
#define WRITEA(J, AV)                                                  \
        {   int c = t + (J) * 256;                                     \
            int m = c / 24, q = c - m * 24;                            \
            h2v p01 = { (_Float16)AV.x, (_Float16)AV.y };              \
            h2v p23 = { (_Float16)AV.z, (_Float16)AV.w };              \
            *reinterpret_cast<h2v*>(&sh.As[m][q * 4])     = p01;       \
            *reinterpret_cast<h2v*>(&sh.As[m][q * 4 + 2]) = p23;       \
        }
        WRITEA(0, av0) WRITEA(1, av1) WRITEA(2, av2)
        WRITEA(3, av3) WRITEA(4, av4) WRITEA(5, av5)
#undef WRITEA
        __syncthreads();

        f32x4 acc[4][4] = {};
#pragma unroll
        for (int ks = 0; ks < 3; ++ks) {
            const int kb = ks * 32 + hi2 * 8;
            f16x8 a[4];
#pragma unroll
            for (int ms = 0; ms < 4; ++ms)
                a[ms] = *reinterpret_cast<const f16x8*>(&sh.As[ms * 16 + lo4][kb]);
#pragma unroll
            for (int ms = 0; ms < 4; ++ms)
#pragma unroll
                for (int ns = 0; ns < 4; ++ns)
                    acc[ms][ns] = __builtin_amdgcn_mfma_f32_16x16x32_f16(
                        a[ms], bfr[ks][ns], acc[ms][ns], 0, 0, 0);
        }

#pragma unroll
        for (int ms = 0; ms < 4; ++ms) {
#pragma unroll
            for (int ns = 0; ns < 4; ++ns) {
                int col = w * 64 + ns * 16 + lo4;
                float bv = bcat[col];
                __half* outp = (col & 128) ? xr0 : xl0;
                int cc = col & 127;
#pragma unroll
                for (int r = 0; r < 4; ++r) {
                    int node = base + ms * 16 + hi2 * 4 + r;
                    if (node < NN)
                        outp[(size_t)node * D1 + cc] = __float2half(acc[ms][ns][r] + bv);
                }
            }
        }
    } else {
        // ================= partition branch (256 thr, PTILE=2048) =================
        for (int tile = half; tile < NPTILES; tile += (gridDim.x >> 1)) {
            const int tb = tile * PTILE;
            const int tc = min(PTILE, EP - tb);
            if (t < NCB) sh.p.cnt[t] = 0;
            __syncthreads();
            unsigned pk0, pk1, pk2, pk3, pk4, pk5, pk6, pk7;
#define LOADK(K, PK)                                              \
            {   int i = t + (K) * 256;                            \
                if (i < tc) {                                     \
                    int e = tb + i; int s, d;                     \
                    if (e < NE) { s = ei[e]; d = ei[NE + e]; }    \
                    else        { s = e - NE; d = s; }            \
                    PK = ((unsigned)d << 16) | (unsigned)s;       \
                    atomicAdd(&sh.p.cnt[d >> CBSH], 1);           \
                } }
            LOADK(0, pk0) LOADK(1, pk1) LOADK(2, pk2) LOADK(3, pk3)
            LOADK(4, pk4) LOADK(5, pk5) LOADK(6, pk6) LOADK(7, pk7)
#undef LOADK
            __syncthreads();
            if (t == 0) {
                int run = 0;
                for (int b = 0; b < NCB; ++b) { sh.p.loff[b] = run; run += sh.p.cnt[b]; }
                sh.p.loff[NCB] = run;
            }
            __syncthreads();
            if (t < NCB) {
                sh.p.gbasel[t] = atomicAdd(&gcnt[t], sh.p.cnt[t]);
                sh.p.lpos[t] = sh.p.loff[t];
            }
            __syncthreads();
#define PLACEK(K, PK)                                             \
            {   int i = t + (K) * 256;                            \
                if (i < tc) {                                     \
                    int cb = (int)(PK >> (16 + CBSH));            \
                    int p = atomicAdd(&sh.p.lpos[cb], 1);         \
                    sh.p.pay[p] = PK;                             \
                } }
            PLACEK(0, pk0) PLACEK(1, pk1) PLACEK(2, pk2) PLACEK(3, pk3)
            PLACEK(4, pk4) PLACEK(5, pk5) PLACEK(6, pk6) PLACEK(7, pk7)
#undef PLACEK
            __syncthreads();
            for (int j = t; j < tc; j += 256) {
                unsigned v = sh.p.pay[j];
                int cb = (int)(v >> (16 + CBSH));
                int pos = sh.p.gbasel[cb] + (j - sh.p.loff[cb]);
                if (pos < GCAP) cstage[(size_t)cb * GCAP + pos] = v;
            }
            __syncthreads();
        }
    }
}

// ---- tiny scan over coarse buckets
__global__ void k_cscan(const int* __restrict__ gcnt, int* __restrict__ gbase,
                        int* __restrict__ rowst)
{
    if (threadIdx.x == 0) {
        int run = 0;
        for (int b = 0; b < NCB; ++b) { gbase[b] = run; run += min(gcnt[b], GCAP); }
        rowst[NN] = run;
    }
}

// ---- pass B: per coarse bucket: 256-dst LDS hist -> rowst; scatter u16 src
__global__ __launch_bounds__(1024) void k_build2(
    const int* __restrict__ gcnt, const int* __restrict__ gbase,
    const unsigned* __restrict__ cstage,
    int* __restrict__ rowst, unsigned short* __restrict__ csr)
{
    const int b = blockIdx.x;
    const int t = threadIdx.x;
    __shared__ int hist[256], sc[256], curs[256];
    const int cnt = min(gcnt[b], GCAP);
    const int base = gbase[b];
    const int d0 = b << CBSH;
    const int nd = min(256, NN - d0);
    if (t < 256) hist[t] = 0;
    __syncthreads();
    const unsigned* __restrict__ src = cstage + (size_t)b * GCAP;
    for (int i = t; i < cnt; i += 1024)
        atomicAdd(&hist[(src[i] >> 16) & 255], 1);
    __syncthreads();
    if (t < 256) sc[t] = hist[t];
    __syncthreads();
    for (int off = 1; off < 256; off <<= 1) {
        int v = 0;
        if (t < 256 && t >= off) v = sc[t - off];
        __syncthreads();
        if (t < 256) sc[t] += v;
        __syncthreads();
    }
    if (t < 256) {
        int excl = sc[t] - hist[t];
        curs[t] = excl;
        if (t < nd) rowst[d0 + t] = base + excl;
    }
    __syncthreads();
    for (int i = t; i < cnt; i += 1024) {
        unsigned v = src[i];
        int p = atomicAdd(&curs[(v >> 16) & 255], 1);
        csr[base + p] = (unsigned short)(v & 0xFFFFu);
    }
}

// ---- layer-0 fused + gemm1 epilogue; pk-fp16 acc; exp2; pipelined index loads
__global__ __launch_bounds__(256) void k_agg0(
    const int* __restrict__ rowst, const unsigned short* __restrict__ csr,
    const __half* __restrict__ xl0, const __half* __restrict__ xr0,
    const float* __restrict__ att0, const float* __restrict__ bias0,
    const float* __restrict__ Wl1, const float* __restrict__ bl1,
    const float* __restrict__ Wr1, const float* __restrict__ br1,
    float* __restrict__ xl1, float* __restrict__ xr1)
{
    const int d = (blockIdx.x * 256 + threadIdx.x) >> 6;
    const int lane = threadIdx.x & 63;
    if (d >= NN) return;
    const int slot  = lane >> 4;
    const int lane4 = lane & 15;
    const int c0 = lane4 * 8;

    uint4 xrw = *reinterpret_cast<const uint4*>(xr0 + (size_t)d * D1 + c0);
    H2U xr01, xr23, xr45, xr67;
    xr01.u = xrw.x; xr23.u = xrw.y; xr45.u = xrw.z; xr67.u = xrw.w;
    float4 atf0 = *reinterpret_cast<const float4*>(att0 + c0);
    float4 atf1 = *reinterpret_cast<const float4*>(att0 + c0 + 4);
    H2U at01, at23, at45, at67;
    at01.h = __floats2half2_rn(atf0.x * LOG2E, atf0.y * LOG2E);
    at23.h = __floats2half2_rn(atf0.z * LOG2E, atf0.w * LOG2E);
    at45.h = __floats2half2_rn(atf1.x * LOG2E, atf1.y * LOG2E);
    at67.h = __floats2half2_rn(atf1.z * LOG2E, atf1.w * LOG2E);
    const _Float16 kneg = (_Float16)NEG;
    const h2v k2 = { kneg, kneg };

    const int rs = rowst[d];
    const int cnt = rowst[d + 1] - rs;
    h2v a01 = {(_Float16)0.f, (_Float16)0.f};
    h2v a23 = a01, a45 = a01, a67 = a01;
    float wsum = 0.f;

#define EDGE(W, VALID)                                                      \
    {   H2U x01, x23, x45, x67;                                             \
        x01.u = (W).x; x23.u = (W).y; x45.u = (W).z; x67.u = (W).w;         \
        h2v s01 = x01.v + xr01.v, s23 = x23.v + xr23.v;                     \
        h2v s45 = x45.v + xr45.v, s67 = x67.v + xr67.v;                     \
        h2v l01 = __builtin_elementwise_max(s01, s01 * k2);                 \
        h2v l23 = __builtin_elementwise_max(s23, s23 * k2);                 \
        h2v l45 = __builtin_elementwise_max(s45, s45 * k2);                 \
        h2v l67 = __builtin_elementwise_max(s67, s67 * k2);                 \
        float p = __builtin_amdgcn_fdot2(l01, at01.v,                       \
                  __builtin_amdgcn_fdot2(l23, at23.v,                       \
                  __builtin_amdgcn_fdot2(l45, at45.v,                       \
                  __builtin_amdgcn_fdot2(l67, at67.v, 0.f, false),          \
                  false), false), false);                                   \
        p += __shfl_xor(p, 1);                                              \
        p += __shfl_xor(p, 2);                                              \
        float wgt = (VALID) ? exp2f(p) : 0.f;                               \
        _Float16 wh = (_Float16)wgt;                                        \
        h2v w2 = { wh, wh };                                                \
        a01 = __builtin_elementwise_fma(w2, x01.v, a01);                    \
        a23 = __builtin_elementwise_fma(w2, x23.v, a23);                    \
        a45 = __builtin_elementwise_fma(w2, x45.v, a45);                    \
        a67 = __builtin_elementwise_fma(w2, x67.v, a67);                    \
        wsum += wgt;                                                        \
    }

    int i = 0;
    if (cnt >= 8) {
        int s0 = csr[rs + slot];
        int s1 = csr[rs + 4 + slot];
        for (; i + 8 <= cnt; i += 8) {
            uint4 w0 = *reinterpret_cast<const uint4*>(xl0 + (size_t)s0 * D1 + c0);
            uint4 w1 = *reinterpret_cast<const uint4*>(xl0 + (size_t)s1 * D1 + c0);
            if (i + 16 <= cnt) {
                s0 = csr[rs + i + 8 + slot];
                s1 = csr[rs + i + 12 + slot];
            }
            EDGE(w0, true);
            EDGE(w1, true);
        }
    }
    for (; i < cnt; i += 4) {
        int e = i + slot;
        bool valid = (e < cnt);
        int s = csr[rs + (valid ? e : 0)];
        uint4 w = *reinterpret_cast<const uint4*>(xl0 + (size_t)s * D1 + c0);
        EDGE(w, valid);
    }
#undef EDGE

    H2U u01, u23, u45, u67;
    u01.v = a01; u23.v = a23; u45.v = a45; u67.v = a67;
    float2 f01 = __half22float2(u01.h), f23 = __half22float2(u23.h);
    float2 f45 = __half22float2(u45.h), f67 = __half22float2(u67.h);
    float acc0 = f01.x, acc1 = f01.y, acc2 = f23.x, acc3 = f23.y;
    float acc4 = f45.x, acc5 = f45.y, acc6 = f67.x, acc7 = f67.y;

#define COMB(V) V += __shfl_xor(V, 16); V += __shfl_xor(V, 32);
    COMB(acc0) COMB(acc1) COMB(acc2) COMB(acc3)
    COMB(acc4) COMB(acc5) COMB(acc6) COMB(acc7)
    COMB(wsum)
#undef COMB

    if (slot == 0) {
        float r = 1.f / (wsum + 1e-16f);
        float4 b0 = *reinterpret_cast<const float4*>(bias0 + c0);
        float4 b1 = *reinterpret_cast<const float4*>(bias0 + c0 + 4);
        float h[8];
        h[0] = fmaxf(acc0 * r + b0.x, 0.f);
        h[1] = fmaxf(acc1 * r + b0.y, 0.f);
        h[2] = fmaxf(acc2 * r + b0.z, 0.f);
        h[3] = fmaxf(acc3 * r + b0.w, 0.f);
        h[4] = fmaxf(acc4 * r + b1.x, 0.f);
        h[5] = fmaxf(acc5 * r + b1.y, 0.f);
        h[6] = fmaxf(acc6 * r + b1.z, 0.f);
        h[7] = fmaxf(acc7 * r + b1.w, 0.f);
        float pl0 = 0.f, pl1 = 0.f, pr0 = 0.f, pr1 = 0.f;
#pragma unroll
        for (int j = 0; j < 8; ++j) {
            float2 wl = *reinterpret_cast<const float2*>(Wl1 + (c0 + j) * 2);
            float2 wr = *reinterpret_cast<const float2*>(Wr1 + (c0 + j) * 2);
            pl0 += h[j] * wl.x; pl1 += h[j] * wl.y;
            pr0 += h[j] * wr.x; pr1 += h[j] * wr.y;
        }
#pragma unroll
        for (int ofs = 1; ofs < 16; ofs <<= 1) {
            pl0 += __shfl_xor(pl0, ofs);
            pl1 += __shfl_xor(pl1, ofs);
            pr0 += __shfl_xor(pr0, ofs);
            pr1 += __shfl_xor(pr1, ofs);
        }
        if (lane4 == 0) {
            *reinterpret_cast<float2*>(xl1 + (size_t)d * 2) =
                make_float2(pl0 + bl1[0], pl1 + bl1[1]);
            *reinterpret_cast<float2*>(xr1 + (size_t)d * 2) =
                make_float2(pr0 + br1[0], pr1 + br1[1]);
        }
    }
}

// ---- layer-1 fused: 4 lanes per dst; strided edges + 2-step shuffle combine
__global__ __launch_bounds__(256) void k_layer1(
    const int* __restrict__ rowst, const unsigned short* __restrict__ csr,
    const float* __restrict__ xl1, const float* __restrict__ xr1,
    const float* __restrict__ att1, const float* __restrict__ bias1,
    float* __restrict__ out)
{
    const int d = (blockIdx.x * 256 + threadIdx.x) >> 2;
    const int sub = threadIdx.x & 3;
    if (d >= NN) return;
    float2 xr = *reinterpret_cast<const float2*>(xr1 + (size_t)d * 2);
    float A0 = att1[0], A1 = att1[1];
    const int rs = rowst[d], re = rowst[d + 1];
    float sum = 0.f, a0 = 0.f, a1 = 0.f;
    for (int i = rs + sub; i < re; i += 4) {
        int s = csr[i];
        float2 xs = *reinterpret_cast<const float2*>(xl1 + (size_t)s * 2);
        float wgt = __expf(lrelu(xs.x + xr.x) * A0 + lrelu(xs.y + xr.y) * A1);
        sum += wgt;
        a0 += wgt * xs.x;
        a1 += wgt * xs.y;
    }
    sum += __shfl_xor(sum, 1); sum += __shfl_xor(sum, 2);
    a0  += __shfl_xor(a0, 1);  a0  += __shfl_xor(a0, 2);
    a1  += __shfl_xor(a1, 1);  a1  += __shfl_xor(a1, 2);
    if (sub == 0) {
        float r = 1.f / (sum + 1e-16f);
        out[(size_t)d * 2]     = a0 * r + bias1[0];
        out[(size_t)d * 2 + 1] = a1 * r + bias1[1];
    }
}

extern "C" void kernel_launch(void* const* d_in, const int* in_sizes, int n_in,
                              void* d_out, int out_size, void* d_ws, size_t ws_size,
                              hipStream_t stream)
{
    const float* x     = (const float*)d_in[0];
    const int*   ei    = (const int*)d_in[1];
    const int*   ts    = (const int*)d_in[2];
    const float* Wt    = (const float*)d_in[3];
    const float* Wl0   = (const float*)d_in[4];
    const float* bl0   = (const float*)d_in[5];
    const float* Wr0   = (const float*)d_in[6];
    const float* br0   = (const float*)d_in[7];
    const float* att0  = (const float*)d_in[8];
    const float* bias0 = (const float*)d_in[9];
    const float* Wl1   = (const float*)d_in[10];
    const float* bl1   = (const float*)d_in[11];
    const float* Wr1   = (const float*)d_in[12];
    const float* br1   = (const float*)d_in[13];
    const float* att1  = (const float*)d_in[14];
    const float* bias1 = (const float*)d_in[15];
    float* out = (float*)d_out;

    char* wsp = (char*)d_ws;
    size_t off = 0;
    auto alloc = [&](size_t bytes) -> void* {
        void* p = wsp + off;
        off += (bytes + 255) & ~(size_t)255;
        return p;
    };
    __half* xl0  = (__half*)alloc((size_t)NN * D1 * 2);
    __half* xr0  = (__half*)alloc((size_t)NN * D1 * 2);
    float* xl1   = (float*)alloc((size_t)NN * 2 * 4);
    float* xr1   = (float*)alloc((size_t)NN * 2 * 4);
    int* rowst   = (int*)alloc((size_t)(NN + 1) * 4);
    unsigned short* csr = (unsigned short*)alloc((size_t)EP * 2);
    int* gcnt        = (int*)alloc((size_t)NCB * 4);
    int* gbase       = (int*)alloc((size_t)NCB * 4);
    unsigned* cstage = (unsigned*)alloc((size_t)NCB * GCAP * 4);
    __half* Btg      = (__half*)alloc((size_t)256 * INDIM * 2);
    float* bcat      = (float*)alloc((size_t)256 * 4);

    (void)hipMemsetAsync(gcnt, 0, (size_t)NCB * 4, stream);
    k_wcast<<<(256 * INDIM + 255) / 256, 256, 0, stream>>>(Wl0, Wr0, bl0, br0, Btg, bcat);

    const int nfused = 2 * ((NGEMM > NPTILES) ? NGEMM : NPTILES);
    k_g0p<<<nfused, 256, 0, stream>>>(x, ts, Wt, Btg, bcat, xl0, xr0, ei, gcnt, cstage);

    k_cscan<<<1, 64, 0, stream>>>(gcnt, gbase, rowst);
    k_build2<<<NCB, 1024, 0, stream>>>(gcnt, gbase, cstage, rowst, csr);

    k_agg0<<<(NN + 3) / 4, 256, 0, stream>>>(rowst, csr, xl0, xr0, att0, bias0,
                                             Wl1, bl1, Wr1, br1, xl1, xr1);
    k_layer1<<<(NN * 4 + 255) / 256, 256, 0, stream>>>(rowst, csr, xl1, xr1, att1, bias1, out);
}

// Round 28
// 127.543 us; speedup vs baseline: 1.1914x; 1.0465x over previous
//
#include <hip/hip_runtime.h>
#include <hip/hip_fp16.h>

#define NN 50000
#define NE 1600000
#define EP (NE + NN)
#define INC 64
#define TDIM 32
#define INDIM 96
#define D1 128
#define NEG 0.2f
#define LOG2E 1.44269504f

#define CBSH 8
#define NCB 196               // ceil(NN / 256)
#define GCAP 9600             // mean 8418 + 12 sigma
#define PTILE 2048            // part tile (256 threads x 8)

#define MT 64                 // gemm0 M-tile rows per block
#define KP 104                // padded K stride (208B rows, 16B aligned)
#define NGEMM ((NN + MT - 1) / MT)            // 782
#define NPTILES ((EP + PTILE - 1) / PTILE)    // 806

typedef _Float16 h2v __attribute__((ext_vector_type(2)));
typedef _Float16 f16x8 __attribute__((ext_vector_type(8)));
typedef float f32x4 __attribute__((ext_vector_type(4)));
union H2U { unsigned u; __half2 h; h2v v; };

__device__ __forceinline__ float lrelu(float v) { return v > 0.f ? v : NEG * v; }

// ---- pack Wl|Wr into transposed fp16 B [256][96] + bias concat + zero gcnt
__global__ __launch_bounds__(256) void k_wcast(
    const float* __restrict__ Wl, const float* __restrict__ Wr,
    const float* __restrict__ bl, const float* __restrict__ br,
    __half* __restrict__ Btg, float* __restrict__ bcat, int* __restrict__ gcnt)
{
    int idx = blockIdx.x * 256 + threadIdx.x;
    if (idx < 256) bcat[idx] = (idx < 128) ? bl[idx] : br[idx - 128];
    if (idx < NCB) gcnt[idx] = 0;
    if (idx >= 256 * INDIM) return;
    int c = idx / INDIM, k = idx - c * INDIM;
    float v = (c < 128) ? Wl[k * D1 + c] : Wr[k * D1 + (c - 128)];
    Btg[idx] = __float2half(v);
}

// ---- fused dispatch: even blocks = gemm0m (MFMA), odd blocks = edge partition
__global__ __launch_bounds__(256) void k_g0p(
    const float* __restrict__ x, const int* __restrict__ ts,
    const float* __restrict__ Wt,
    const __half* __restrict__ Btg, const float* __restrict__ bcat,
    __half* __restrict__ xl0, __half* __restrict__ xr0,
    const int* __restrict__ ei, int* __restrict__ gcnt,
    unsigned* __restrict__ cstage)
{
    __shared__ union SH {
        _Float16 As[MT][KP];
        struct {
            int cnt[NCB], loff[NCB + 1], gbasel[NCB], lpos[NCB];
            unsigned pay[PTILE];
        } p;
    } sh;
    const int t = threadIdx.x;
    const int half = blockIdx.x >> 1;

    if ((blockIdx.x & 1) == 0) {
        // ================= gemm0m branch =================
        if (half >= NGEMM) return;
        const int base = half * MT;
        const float4* __restrict__ x4  = reinterpret_cast<const float4*>(x);
        const float4* __restrict__ wt4 = reinterpret_cast<const float4*>(Wt);

        const int lane = t & 63;
        const int w = t >> 6;
        const int lo4 = lane & 15;
        const int hi2 = lane >> 4;

        f16x8 bfr[3][4];
#pragma unroll
        for (int ks = 0; ks < 3; ++ks)
#pragma unroll
            for (int ns = 0; ns < 4; ++ns)
                bfr[ks][ns] = *reinterpret_cast<const f16x8*>(
                    Btg + (size_t)(w * 64 + ns * 16 + lo4) * INDIM + ks * 32 + hi2 * 8);

        float4 av0, av1, av2, av3, av4, av5;
#define LOADA(J, AV)                                                   \
        {   int c = t + (J) * 256;                                     \
            int m = c / 24, q = c - m * 24;                            \
            int n = base + m;                                          \
            if (n < NN)                                                \
                AV = (q < 16) ? x4[(size_t)n * 16 + q]                 \
                              : wt4[(size_t)ts[n] * 8 + (q - 16)];     \
            else AV = make_float4(0.f, 0.f, 0.f, 0.f);                 \
        }
        LOADA(0, av0) LOADA(1, av1) LOADA(2, av2)
        LOADA(3, av3) LOADA(4, av4) LOADA(5, av5)
#undef LOADA
#define WRITEA(J, AV)                                                  \
        {   int c = t + (J) * 256;                                     \
            int m = c / 24, q = c - m * 24;                            \
            h2v p01 = { (_Float16)AV.x, (_Float16)AV.y };              \
            h2v p23 = { (_Float16)AV.z, (_Float16)AV.w };              \
            *reinterpret_cast<h2v*>(&sh.As[m][q * 4])     = p01;       \
            *reinterpret_cast<h2v*>(&sh.As[m][q * 4 + 2]) = p23;       \
        }
        WRITEA(0, av0) WRITEA(1, av1) WRITEA(2, av2)
        WRITEA(3, av3) WRITEA(4, av4) WRITEA(5, av5)
#undef WRITEA
        __syncthreads();

        f32x4 acc[4][4] = {};
#pragma unroll
        for (int ks = 0; ks < 3; ++ks) {
            const int kb = ks * 32 + hi2 * 8;
            f16x8 a[4];
#pragma unroll
            for (int ms = 0; ms < 4; ++ms)
                a[ms] = *reinterpret_cast<const f16x8*>(&sh.As[ms * 16 + lo4][kb]);
#pragma unroll
            for (int ms = 0; ms < 4; ++ms)
#pragma unroll
                for (int ns = 0; ns < 4; ++ns)
                    acc[ms][ns] = __builtin_amdgcn_mfma_f32_16x16x32_f16(
                        a[ms], bfr[ks][ns], acc[ms][ns], 0, 0, 0);
        }

#pragma unroll
        for (int ms = 0; ms < 4; ++ms) {
#pragma unroll
            for (int ns = 0; ns < 4; ++ns) {
                int col = w * 64 + ns * 16 + lo4;
                float bv = bcat[col];
                __half* outp = (col & 128) ? xr0 : xl0;
                int cc = col & 127;
#pragma unroll
                for (int r = 0; r < 4; ++r) {
                    int node = base + ms * 16 + hi2 * 4 + r;
                    if (node < NN)
                        outp[(size_t)node * D1 + cc] = __float2half(acc[ms][ns][r] + bv);
                }
            }
        }
    } else {
        // ================= partition branch (256 thr, PTILE=2048) =================
        for (int tile = half; tile < NPTILES; tile += (gridDim.x >> 1)) {
            const int tb = tile * PTILE;
            const int tc = min(PTILE, EP - tb);
            if (t < NCB) sh.p.cnt[t] = 0;
            __syncthreads();
            unsigned pk0, pk1, pk2, pk3, pk4, pk5, pk6, pk7;
#define LOADK(K, PK)                                              \
            {   int i = t + (K) * 256;                            \
                if (i < tc) {                                     \
                    int e = tb + i; int s, d;                     \
                    if (e < NE) { s = ei[e]; d = ei[NE + e]; }    \
                    else        { s = e - NE; d = s; }            \
                    PK = ((unsigned)d << 16) | (unsigned)s;       \
                    atomicAdd(&sh.p.cnt[d >> CBSH], 1);           \
                } }
            LOADK(0, pk0) LOADK(1, pk1) LOADK(2, pk2) LOADK(3, pk3)
            LOADK(4, pk4) LOADK(5, pk5) LOADK(6, pk6) LOADK(7, pk7)
#undef LOADK
            __syncthreads();
            if (t == 0) {
                int run = 0;
                for (int b = 0; b < NCB; ++b) { sh.p.loff[b] = run; run += sh.p.cnt[b]; }
                sh.p.loff[NCB] = run;
            }
            __syncthreads();
            if (t < NCB) {
                sh.p.gbasel[t] = atomicAdd(&gcnt[t], sh.p.cnt[t]);
                sh.p.lpos[t] = sh.p.loff[t];
            }
            __syncthreads();
#define PLACEK(K, PK)                                             \
            {   int i = t + (K) * 256;                            \
                if (i < tc) {                                     \
                    int cb = (int)(PK >> (16 + CBSH));            \
                    int p = atomicAdd(&sh.p.lpos[cb], 1);         \
                    sh.p.pay[p] = PK;                             \
                } }
            PLACEK(0, pk0) PLACEK(1, pk1) PLACEK(2, pk2) PLACEK(3, pk3)
            PLACEK(4, pk4) PLACEK(5, pk5) PLACEK(6, pk6) PLACEK(7, pk7)
#undef PLACEK
            __syncthreads();
            for (int j = t; j < tc; j += 256) {
                unsigned v = sh.p.pay[j];
                int cb = (int)(v >> (16 + CBSH));
                int pos = sh.p.gbasel[cb] + (j - sh.p.loff[cb]);
                if (pos < GCAP) cstage[(size_t)cb * GCAP + pos] = v;
            }
            __syncthreads();
        }
    }
}

// ---- pass B: per coarse bucket: self-scan of gcnt -> gbase; 256-dst hist; scatter
__global__ __launch_bounds__(1024) void k_build2(
    const int* __restrict__ gcnt,
    const unsigned* __restrict__ cstage,
    int* __restrict__ rowst, unsigned short* __restrict__ csr)
{
    const int b = blockIdx.x;
    const int t = threadIdx.x;
    __shared__ int hist[256], sc[256], curs[256];
    __shared__ int basesh;
    const int cnt = min(gcnt[b], GCAP);
    const int d0 = b << CBSH;
    const int nd = min(256, NN - d0);
    if (t < 256) hist[t] = 0;
    // self-computed exclusive prefix over buckets (196 entries, L2-cached)
    if (t == 0) {
        int run = 0;
        for (int bb = 0; bb < b; ++bb) run += min(gcnt[bb], GCAP);
        basesh = run;
        if (b == NCB - 1) rowst[NN] = run + cnt;
    }
    __syncthreads();
    const int base = basesh;
    const unsigned* __restrict__ src = cstage + (size_t)b * GCAP;
    for (int i = t; i < cnt; i += 1024)
        atomicAdd(&hist[(src[i] >> 16) & 255], 1);
    __syncthreads();
    if (t < 256) sc[t] = hist[t];
    __syncthreads();
    for (int off = 1; off < 256; off <<= 1) {
        int v = 0;
        if (t < 256 && t >= off) v = sc[t - off];
        __syncthreads();
        if (t < 256) sc[t] += v;
        __syncthreads();
    }
    if (t < 256) {
        int excl = sc[t] - hist[t];
        curs[t] = excl;
        if (t < nd) rowst[d0 + t] = base + excl;
    }
    __syncthreads();
    for (int i = t; i < cnt; i += 1024) {
        unsigned v = src[i];
        int p = atomicAdd(&curs[(v >> 16) & 255], 1);
        csr[base + p] = (unsigned short)(v & 0xFFFFu);
    }
}

// ---- layer-0 fused + gemm1 epilogue; pk-fp16 acc; exp2; pipelined index loads
__global__ __launch_bounds__(256) void k_agg0(
    const int* __restrict__ rowst, const unsigned short* __restrict__ csr,
    const __half* __restrict__ xl0, const __half* __restrict__ xr0,
    const float* __restrict__ att0, const float* __restrict__ bias0,
    const float* __restrict__ Wl1, const float* __restrict__ bl1,
    const float* __restrict__ Wr1, const float* __restrict__ br1,
    float* __restrict__ xl1, float* __restrict__ xr1)
{
    const int d = (blockIdx.x * 256 + threadIdx.x) >> 6;
    const int lane = threadIdx.x & 63;
    if (d >= NN) return;
    const int slot  = lane >> 4;
    const int lane4 = lane & 15;
    const int c0 = lane4 * 8;

    uint4 xrw = *reinterpret_cast<const uint4*>(xr0 + (size_t)d * D1 + c0);
    H2U xr01, xr23, xr45, xr67;
    xr01.u = xrw.x; xr23.u = xrw.y; xr45.u = xrw.z; xr67.u = xrw.w;
    float4 atf0 = *reinterpret_cast<const float4*>(att0 + c0);
    float4 atf1 = *reinterpret_cast<const float4*>(att0 + c0 + 4);
    H2U at01, at23, at45, at67;
    at01.h = __floats2half2_rn(atf0.x * LOG2E, atf0.y * LOG2E);
    at23.h = __floats2half2_rn(atf0.z * LOG2E, atf0.w * LOG2E);
    at45.h = __floats2half2_rn(atf1.x * LOG2E, atf1.y * LOG2E);
    at67.h = __floats2half2_rn(atf1.z * LOG2E, atf1.w * LOG2E);
    const _Float16 kneg = (_Float16)NEG;
    const h2v k2 = { kneg, kneg };

    const int rs = rowst[d];
    const int cnt = rowst[d + 1] - rs;
    h2v a01 = {(_Float16)0.f, (_Float16)0.f};
    h2v a23 = a01, a45 = a01, a67 = a01;
    float wsum = 0.f;

#define EDGE(W, VALID)                                                      \
    {   H2U x01, x23, x45, x67;                                             \
        x01.u = (W).x; x23.u = (W).y; x45.u = (W).z; x67.u = (W).w;         \
        h2v s01 = x01.v + xr01.v, s23 = x23.v + xr23.v;                     \
        h2v s45 = x45.v + xr45.v, s67 = x67.v + xr67.v;                     \
        h2v l01 = __builtin_elementwise_max(s01, s01 * k2);                 \
        h2v l23 = __builtin_elementwise_max(s23, s23 * k2);                 \
        h2v l45 = __builtin_elementwise_max(s45, s45 * k2);                 \
        h2v l67 = __builtin_elementwise_max(s67, s67 * k2);                 \
        float p = __builtin_amdgcn_fdot2(l01, at01.v,                       \
                  __builtin_amdgcn_fdot2(l23, at23.v,                       \
                  __builtin_amdgcn_fdot2(l45, at45.v,                       \
                  __builtin_amdgcn_fdot2(l67, at67.v, 0.f, false),          \
                  false), false), false);                                   \
        p += __shfl_xor(p, 1);                                              \
        p += __shfl_xor(p, 2);                                              \
        float wgt = (VALID) ? exp2f(p) : 0.f;                               \
        _Float16 wh = (_Float16)wgt;                                        \
        h2v w2 = { wh, wh };                                                \
        a01 = __builtin_elementwise_fma(w2, x01.v, a01);                    \
        a23 = __builtin_elementwise_fma(w2, x23.v, a23);                    \
        a45 = __builtin_elementwise_fma(w2, x45.v, a45);                    \
        a67 = __builtin_elementwise_fma(w2, x67.v, a67);                    \
        wsum += wgt;                                                        \
    }

    int i = 0;
    if (cnt >= 8) {
        int s0 = csr[rs + slot];
        int s1 = csr[rs + 4 + slot];
        for (; i + 8 <= cnt; i += 8) {
            uint4 w0 = *reinterpret_cast<const uint4*>(xl0 + (size_t)s0 * D1 + c0);
            uint4 w1 = *reinterpret_cast<const uint4*>(xl0 + (size_t)s1 * D1 + c0);
            if (i + 16 <= cnt) {
                s0 = csr[rs + i + 8 + slot];
                s1 = csr[rs + i + 12 + slot];
            }
            EDGE(w0, true);
            EDGE(w1, true);
        }
    }
    for (; i < cnt; i += 4) {
        int e = i + slot;
        bool valid = (e < cnt);
        int s = csr[rs + (valid ? e : 0)];
        uint4 w = *reinterpret_cast<const uint4*>(xl0 + (size_t)s * D1 + c0);
        EDGE(w, valid);
    }
#undef EDGE

    H2U u01, u23, u45, u67;
    u01.v = a01; u23.v = a23; u45.v = a45; u67.v = a67;
    float2 f01 = __half22float2(u01.h), f23 = __half22float2(u23.h);
    float2 f45 = __half22float2(u45.h), f67 = __half22float2(u67.h);
    float acc0 = f01.x, acc1 = f01.y, acc2 = f23.x, acc3 = f23.y;
    float acc4 = f45.x, acc5 = f45.y, acc6 = f67.x, acc7 = f67.y;

#define COMB(V) V += __shfl_xor(V, 16); V += __shfl_xor(V, 32);
    COMB(acc0) COMB(acc1) COMB(acc2) COMB(acc3)
    COMB(acc4) COMB(acc5) COMB(acc6) COMB(acc7)
    COMB(wsum)
#undef COMB

    if (slot == 0) {
        float r = 1.f / (wsum + 1e-16f);
        float4 b0 = *reinterpret_cast<const float4*>(bias0 + c0);
        float4 b1 = *reinterpret_cast<const float4*>(bias0 + c0 + 4);
        float h[8];
        h[0] = fmaxf(acc0 * r + b0.x, 0.f);
        h[1] = fmaxf(acc1 * r + b0.y, 0.f);
        h[2] = fmaxf(acc2 * r + b0.z, 0.f);
        h[3] = fmaxf(acc3 * r + b0.w, 0.f);
        h[4] = fmaxf(acc4 * r + b1.x, 0.f);
        h[5] = fmaxf(acc5 * r + b1.y, 0.f);
        h[6] = fmaxf(acc6 * r + b1.z, 0.f);
        h[7] = fmaxf(acc7 * r + b1.w, 0.f);
        float pl0 = 0.f, pl1 = 0.f, pr0 = 0.f, pr1 = 0.f;
#pragma unroll
        for (int j = 0; j < 8; ++j) {
            float2 wl = *reinterpret_cast<const float2*>(Wl1 + (c0 + j) * 2);
            float2 wr = *reinterpret_cast<const float2*>(Wr1 + (c0 + j) * 2);
            pl0 += h[j] * wl.x; pl1 += h[j] * wl.y;
            pr0 += h[j] * wr.x; pr1 += h[j] * wr.y;
        }
#pragma unroll
        for (int ofs = 1; ofs < 16; ofs <<= 1) {
            pl0 += __shfl_xor(pl0, ofs);
            pl1 += __shfl_xor(pl1, ofs);
            pr0 += __shfl_xor(pr0, ofs);
            pr1 += __shfl_xor(pr1, ofs);
        }
        if (lane4 == 0) {
            *reinterpret_cast<float2*>(xl1 + (size_t)d * 2) =
                make_float2(pl0 + bl1[0], pl1 + bl1[1]);
            *reinterpret_cast<float2*>(xr1 + (size_t)d * 2) =
                make_float2(pr0 + br1[0], pr1 + br1[1]);
        }
    }
}

// ---- layer-1 fused: 4 lanes per dst; strided edges + 2-step shuffle combine
__global__ __launch_bounds__(256) void k_layer1(
    const int* __restrict__ rowst, const unsigned short* __restrict__ csr,
    const float* __restrict__ xl1, const float* __restrict__ xr1,
    const float* __restrict__ att1, const float* __restrict__ bias1,
    float* __restrict__ out)
{
    const int d = (blockIdx.x * 256 + threadIdx.x) >> 2;
    const int sub = threadIdx.x & 3;
    if (d >= NN) return;
    float2 xr = *reinterpret_cast<const float2*>(xr1 + (size_t)d * 2);
    float A0 = att1[0], A1 = att1[1];
    const int rs = rowst[d], re = rowst[d + 1];
    float sum = 0.f, a0 = 0.f, a1 = 0.f;
    for (int i = rs + sub; i < re; i += 4) {
        int s = csr[i];
        float2 xs = *reinterpret_cast<const float2*>(xl1 + (size_t)s * 2);
        float wgt = __expf(lrelu(xs.x + xr.x) * A0 + lrelu(xs.y + xr.y) * A1);
        sum += wgt;
        a0 += wgt * xs.x;
        a1 += wgt * xs.y;
    }
    sum += __shfl_xor(sum, 1); sum += __shfl_xor(sum, 2);
    a0  += __shfl_xor(a0, 1);  a0  += __shfl_xor(a0, 2);
    a1  += __shfl_xor(a1, 1);  a1  += __shfl_xor(a1, 2);
    if (sub == 0) {
        float r = 1.f / (sum + 1e-16f);
        out[(size_t)d * 2]     = a0 * r + bias1[0];
        out[(size_t)d * 2 + 1] = a1 * r + bias1[1];
    }
}

extern "C" void kernel_launch(void* const* d_in, const int* in_sizes, int n_in,
                              void* d_out, int out_size, void* d_ws, size_t ws_size,
                              hipStream_t stream)
{
    const float* x     = (const float*)d_in[0];
    const int*   ei    = (const int*)d_in[1];
    const int*   ts    = (const int*)d_in[2];
    const float* Wt    = (const float*)d_in[3];
    const float* Wl0   = (const float*)d_in[4];
    const float* bl0   = (const float*)d_in[5];
    const float* Wr0   = (const float*)d_in[6];
    const float* br0   = (const float*)d_in[7];
    const float* att0  = (const float*)d_in[8];
    const float* bias0 = (const float*)d_in[9];
    const float* Wl1   = (const float*)d_in[10];
    const float* bl1   = (const float*)d_in[11];
    const float* Wr1   = (const float*)d_in[12];
    const float* br1   = (const float*)d_in[13];
    const float* att1  = (const float*)d_in[14];
    const float* bias1 = (const float*)d_in[15];
    float* out = (float*)d_out;

    char* wsp = (char*)d_ws;
    size_t off = 0;
    auto alloc = [&](size_t bytes) -> void* {
        void* p = wsp + off;
        off += (bytes + 255) & ~(size_t)255;
        return p;
    };
    __half* xl0  = (__half*)alloc((size_t)NN * D1 * 2);
    __half* xr0  = (__half*)alloc((size_t)NN * D1 * 2);
    float* xl1   = (float*)alloc((size_t)NN * 2 * 4);
    float* xr1   = (float*)alloc((size_t)NN * 2 * 4);
    int* rowst   = (int*)alloc((size_t)(NN + 1) * 4);
    unsigned short* csr = (unsigned short*)alloc((size_t)EP * 2);
    int* gcnt        = (int*)alloc((size_t)NCB * 4);
    unsigned* cstage = (unsigned*)alloc((size_t)NCB * GCAP * 4);
    __half* Btg      = (__half*)alloc((size_t)256 * INDIM * 2);
    float* bcat      = (float*)alloc((size_t)256 * 4);

    k_wcast<<<(256 * INDIM + 255) / 256, 256, 0, stream>>>(Wl0, Wr0, bl0, br0, Btg, bcat, gcnt);

    const int nfused = 2 * ((NGEMM > NPTILES) ? NGEMM : NPTILES);
    k_g0p<<<nfused, 256, 0, stream>>>(x, ts, Wt, Btg, bcat, xl0, xr0, ei, gcnt, cstage);

    k_build2<<<NCB, 1024, 0, stream>>>(gcnt, cstage, rowst, csr);

    k_agg0<<<(NN + 3) / 4, 256, 0, stream>>>(rowst, csr, xl0, xr0, att0, bias0,
                                             Wl1, bl1, Wr1, br1, xl1, xr1);
    k_layer1<<<(NN * 4 + 255) / 256, 256, 0, stream>>>(rowst, csr, xl1, xr1, att1, bias1, out);
}

// Round 29
// 119.182 us; speedup vs baseline: 1.2749x; 1.0702x over previous
//
#include <hip/hip_runtime.h>
#include <hip/hip_fp16.h>

#define NN 50000
#define NE 1600000
#define EP (NE + NN)
#define INC 64
#define TDIM 32
#define INDIM 96
#define D1 128
#define NEG 0.2f
#define LOG2E 1.44269504f

#define CBSH 8
#define NCB 196               // ceil(NN / 256)
#define GCAP 9600             // mean 8418 + 12 sigma
#define PTILE 2048            // part tile (256 threads x 8)

#define MT 32                 // gemm0 M-tile rows per block (halved: more blocks, shorter chains)
#define KP 104                // padded K stride (208B rows, 16B aligned)
#define NGEMM ((NN + MT - 1) / MT)            // 1563
#define NPTILES ((EP + PTILE - 1) / PTILE)    // 806

typedef _Float16 h2v __attribute__((ext_vector_type(2)));
typedef _Float16 f16x8 __attribute__((ext_vector_type(8)));
typedef float f32x4 __attribute__((ext_vector_type(4)));
union H2U { unsigned u; __half2 h; h2v v; };

__device__ __forceinline__ float lrelu(float v) { return v > 0.f ? v : NEG * v; }

// ---- pack Wl|Wr into transposed fp16 B [256][96] + bias concat + zero gcnt
__global__ __launch_bounds__(256) void k_wcast(
    const float* __restrict__ Wl, const float* __restrict__ Wr,
    const float* __restrict__ bl, const float* __restrict__ br,
    __half* __restrict__ Btg, float* __restrict__ bcat, int* __restrict__ gcnt)
{
    int idx = blockIdx.x * 256 + threadIdx.x;
    if (idx < 256) bcat[idx] = (idx < 128) ? bl[idx] : br[idx - 128];
    if (idx < NCB) gcnt[idx] = 0;
    if (idx >= 256 * INDIM) return;
    int c = idx / INDIM, k = idx - c * INDIM;
    float v = (c < 128) ? Wl[k * D1 + c] : Wr[k * D1 + (c - 128)];
    Btg[idx] = __float2half(v);
}

// ---- fused dispatch: even blocks = gemm0m (MFMA, MT=32), odd blocks = edge partition
__global__ __launch_bounds__(256) void k_g0p(
    const float* __restrict__ x, const int* __restrict__ ts,
    const float* __restrict__ Wt,
    const __half* __restrict__ Btg, const float* __restrict__ bcat,
    __half* __restrict__ xl0, __half* __restrict__ xr0,
    const int* __restrict__ ei, int* __restrict__ gcnt,
    unsigned* __restrict__ cstage)
{
    __shared__ union SH {
        _Float16 As[MT][KP];
        struct {
            int cnt[NCB], loff[NCB + 1], gbasel[NCB], lpos[NCB];
            unsigned pay[PTILE];
        } p;
    } sh;
    const int t = threadIdx.x;
    const int half = blockIdx.x >> 1;

    if ((blockIdx.x & 1) == 0) {
        // ================= gemm0m branch (MT=32) =================
        if (half >= NGEMM) return;
        const int base = half * MT;
        const float4* __restrict__ x4  = reinterpret_cast<const float4*>(x);
        const float4* __restrict__ wt4 = reinterpret_cast<const float4*>(Wt);

        const int lane = t & 63;
        const int w = t >> 6;
        const int lo4 = lane & 15;
        const int hi2 = lane >> 4;

        f16x8 bfr[3][4];
#pragma unroll
        for (int ks = 0; ks < 3; ++ks)
#pragma unroll
            for (int ns = 0; ns < 4; ++ns)
                bfr[ks][ns] = *reinterpret_cast<const f16x8*>(
                    Btg + (size_t)(w * 64 + ns * 16 + lo4) * INDIM + ks * 32 + hi2 * 8);

        float4 av0, av1, av2;
#define LOADA(J, AV)                                                   \
        {   int c = t + (J) * 256;                                     \
            int m = c / 24, q = c - m * 24;                            \
            int n = base + m;                                          \
            if (n < NN)                                                \
                AV = (q < 16) ? x4[(size_t)n * 16 + q]                 \
                              : wt4[(size_t)ts[n] * 8 + (q - 16)];     \
            else AV = make_float4(0.f, 0.f, 0.f, 0.f);                 \
        }
        LOADA(0, av0) LOADA(1, av1) LOADA(2, av2)
#undef LOADA
#define WRITEA(J, AV)                                                  \
        {   int c = t + (J) * 256;                                     \
            int m = c / 24, q = c - m * 24;                            \
            h2v p01 = { (_Float16)AV.x, (_Float16)AV.y };              \
            h2v p23 = { (_Float16)AV.z, (_Float16)AV.w };              \
            *reinterpret_cast<h2v*>(&sh.As[m][q * 4])     = p01;       \
            *reinterpret_cast<h2v*>(&sh.As[m][q * 4 + 2]) = p23;       \
        }
        WRITEA(0, av0) WRITEA(1, av1) WRITEA(2, av2)
#undef WRITEA
        __syncthreads();

        f32x4 acc[2][4] = {};
#pragma unroll
        for (int ks = 0; ks < 3; ++ks) {
            const int kb = ks * 32 + hi2 * 8;
            f16x8 a[2];
#pragma unroll
            for (int ms = 0; ms < 2; ++ms)
                a[ms] = *reinterpret_cast<const f16x8*>(&sh.As[ms * 16 + lo4][kb]);
#pragma unroll
            for (int ms = 0; ms < 2; ++ms)
#pragma unroll
                for (int ns = 0; ns < 4; ++ns)
                    acc[ms][ns] = __builtin_amdgcn_mfma_f32_16x16x32_f16(
                        a[ms], bfr[ks][ns], acc[ms][ns], 0, 0, 0);
        }

#pragma unroll
        for (int ms = 0; ms < 2; ++ms) {
#pragma unroll
            for (int ns = 0; ns < 4; ++ns) {
                int col = w * 64 + ns * 16 + lo4;
                float bv = bcat[col];
                __half* outp = (col & 128) ? xr0 : xl0;
                int cc = col & 127;
#pragma unroll
                for (int r = 0; r < 4; ++r) {
                    int node = base + ms * 16 + hi2 * 4 + r;
                    if (node < NN)
                        outp[(size_t)node * D1 + cc] = __float2half(acc[ms][ns][r] + bv);
                }
            }
        }
    } else {
        // ================= partition branch (256 thr, PTILE=2048) =================
        for (int tile = half; tile < NPTILES; tile += (gridDim.x >> 1)) {
            const int tb = tile * PTILE;
            const int tc = min(PTILE, EP - tb);
            if (t < NCB) sh.p.cnt[t] = 0;
            __syncthreads();
            unsigned pk0, pk1, pk2, pk3, pk4, pk5, pk6, pk7;
#define LOADK(K, PK)                                              \
            {   int i = t + (K) * 256;                            \
                if (i < tc) {                                     \
                    int e = tb + i; int s, d;                     \
                    if (e < NE) { s = ei[e]; d = ei[NE + e]; }    \
                    else        { s = e - NE; d = s; }            \
                    PK = ((unsigned)d << 16) | (unsigned)s;       \
                    atomicAdd(&sh.p.cnt[d >> CBSH], 1);           \
                } }
            LOADK(0, pk0) LOADK(1, pk1) LOADK(2, pk2) LOADK(3, pk3)
            LOADK(4, pk4) LOADK(5, pk5) LOADK(6, pk6) LOADK(7, pk7)
#undef LOADK
            __syncthreads();
            if (t == 0) {
                int run = 0;
                for (int b = 0; b < NCB; ++b) { sh.p.loff[b] = run; run += sh.p.cnt[b]; }
                sh.p.loff[NCB] = run;
            }
            __syncthreads();
            if (t < NCB) {
                sh.p.gbasel[t] = atomicAdd(&gcnt[t], sh.p.cnt[t]);
                sh.p.lpos[t] = sh.p.loff[t];
            }
            __syncthreads();
#define PLACEK(K, PK)                                             \
            {   int i = t + (K) * 256;                            \
                if (i < tc) {                                     \
                    int cb = (int)(PK >> (16 + CBSH));            \
                    int p = atomicAdd(&sh.p.lpos[cb], 1);         \
                    sh.p.pay[p] = PK;                             \
                } }
            PLACEK(0, pk0) PLACEK(1, pk1) PLACEK(2, pk2) PLACEK(3, pk3)
            PLACEK(4, pk4) PLACEK(5, pk5) PLACEK(6, pk6) PLACEK(7, pk7)
#undef PLACEK
            __syncthreads();
            for (int j = t; j < tc; j += 256) {
                unsigned v = sh.p.pay[j];
                int cb = (int)(v >> (16 + CBSH));
                int pos = sh.p.gbasel[cb] + (j - sh.p.loff[cb]);
                if (pos < GCAP) cstage[(size_t)cb * GCAP + pos] = v;
            }
            __syncthreads();
        }
    }
}

// ---- pass B: per coarse bucket: self-scan of gcnt -> gbase; 256-dst hist; scatter
__global__ __launch_bounds__(1024) void k_build2(
    const int* __restrict__ gcnt,
    const unsigned* __restrict__ cstage,
    int* __restrict__ rowst, unsigned short* __restrict__ csr)
{
    const int b = blockIdx.x;
    const int t = threadIdx.x;
    __shared__ int hist[256], sc[256], curs[256];
    __shared__ int basesh;
    const int cnt = min(gcnt[b], GCAP);
    const int d0 = b << CBSH;
    const int nd = min(256, NN - d0);
    if (t < 256) hist[t] = 0;
    if (t == 0) {
        int run = 0;
        for (int bb = 0; bb < b; ++bb) run += min(gcnt[bb], GCAP);
        basesh = run;
        if (b == NCB - 1) rowst[NN] = run + cnt;
    }
    __syncthreads();
    const int base = basesh;
    const unsigned* __restrict__ src = cstage + (size_t)b * GCAP;
    for (int i = t; i < cnt; i += 1024)
        atomicAdd(&hist[(src[i] >> 16) & 255], 1);
    __syncthreads();
    if (t < 256) sc[t] = hist[t];
    __syncthreads();
    for (int off = 1; off < 256; off <<= 1) {
        int v = 0;
        if (t < 256 && t >= off) v = sc[t - off];
        __syncthreads();
        if (t < 256) sc[t] += v;
        __syncthreads();
    }
    if (t < 256) {
        int excl = sc[t] - hist[t];
        curs[t] = excl;
        if (t < nd) rowst[d0 + t] = base + excl;
    }
    __syncthreads();
    for (int i = t; i < cnt; i += 1024) {
        unsigned v = src[i];
        int p = atomicAdd(&curs[(v >> 16) & 255], 1);
        csr[base + p] = (unsigned short)(v & 0xFFFFu);
    }
}

// ---- layer-0 fused + gemm1 epilogue; pk-fp16 acc; exp2; pipelined index loads
__global__ __launch_bounds__(256) void k_agg0(
    const int* __restrict__ rowst, const unsigned short* __restrict__ csr,
    const __half* __restrict__ xl0, const __half* __restrict__ xr0,
    const float* __restrict__ att0, const float* __restrict__ bias0,
    const float* __restrict__ Wl1, const float* __restrict__ bl1,
    const float* __restrict__ Wr1, const float* __restrict__ br1,
    float* __restrict__ xl1, float* __restrict__ xr1)
{
    const int d = (blockIdx.x * 256 + threadIdx.x) >> 6;
    const int lane = threadIdx.x & 63;
    if (d >= NN) return;
    const int slot  = lane >> 4;
    const int lane4 = lane & 15;
    const int c0 = lane4 * 8;

    uint4 xrw = *reinterpret_cast<const uint4*>(xr0 + (size_t)d * D1 + c0);
    H2U xr01, xr23, xr45, xr67;
    xr01.u = xrw.x; xr23.u = xrw.y; xr45.u = xrw.z; xr67.u = xrw.w;
    float4 atf0 = *reinterpret_cast<const float4*>(att0 + c0);
    float4 atf1 = *reinterpret_cast<const float4*>(att0 + c0 + 4);
    H2U at01, at23, at45, at67;
    at01.h = __floats2half2_rn(atf0.x * LOG2E, atf0.y * LOG2E);
    at23.h = __floats2half2_rn(atf0.z * LOG2E, atf0.w * LOG2E);
    at45.h = __floats2half2_rn(atf1.x * LOG2E, atf1.y * LOG2E);
    at67.h = __floats2half2_rn(atf1.z * LOG2E, atf1.w * LOG2E);
    const _Float16 kneg = (_Float16)NEG;
    const h2v k2 = { kneg, kneg };

    const int rs = rowst[d];
    const int cnt = rowst[d + 1] - rs;
    h2v a01 = {(_Float16)0.f, (_Float16)0.f};
    h2v a23 = a01, a45 = a01, a67 = a01;
    float wsum = 0.f;

#define EDGE(W, VALID)                                                      \
    {   H2U x01, x23, x45, x67;                                             \
        x01.u = (W).x; x23.u = (W).y; x45.u = (W).z; x67.u = (W).w;         \
        h2v s01 = x01.v + xr01.v, s23 = x23.v + xr23.v;                     \
        h2v s45 = x45.v + xr45.v, s67 = x67.v + xr67.v;                     \
        h2v l01 = __builtin_elementwise_max(s01, s01 * k2);                 \
        h2v l23 = __builtin_elementwise_max(s23, s23 * k2);                 \
        h2v l45 = __builtin_elementwise_max(s45, s45 * k2);                 \
        h2v l67 = __builtin_elementwise_max(s67, s67 * k2);                 \
        float p = __builtin_amdgcn_fdot2(l01, at01.v,                       \
                  __builtin_amdgcn_fdot2(l23, at23.v,                       \
                  __builtin_amdgcn_fdot2(l45, at45.v,                       \
                  __builtin_amdgcn_fdot2(l67, at67.v, 0.f, false),          \
                  false), false), false);                                   \
        p += __shfl_xor(p, 1);                                              \
        p += __shfl_xor(p, 2);                                              \
        float wgt = (VALID) ? exp2f(p) : 0.f;                               \
        _Float16 wh = (_Float16)wgt;                                        \
        h2v w2 = { wh, wh };                                                \
        a01 = __builtin_elementwise_fma(w2, x01.v, a01);                    \
        a23 = __builtin_elementwise_fma(w2, x23.v, a23);                    \
        a45 = __builtin_elementwise_fma(w2, x45.v, a45);                    \
        a67 = __builtin_elementwise_fma(w2, x67.v, a67);                    \
        wsum += wgt;                                                        \
    }

    int i = 0;
    if (cnt >= 8) {
        int s0 = csr[rs + slot];
        int s1 = csr[rs + 4 + slot];
        for (; i + 8 <= cnt; i += 8) {
            uint4 w0 = *reinterpret_cast<const uint4*>(xl0 + (size_t)s0 * D1 + c0);
            uint4 w1 = *reinterpret_cast<const uint4*>(xl0 + (size_t)s1 * D1 + c0);
            if (i + 16 <= cnt) {
                s0 = csr[rs + i + 8 + slot];
                s1 = csr[rs + i + 12 + slot];
            }
            EDGE(w0, true);
            EDGE(w1, true);
        }
    }
    for (; i < cnt; i += 4) {
        int e = i + slot;
        bool valid = (e < cnt);
        int s = csr[rs + (valid ? e : 0)];
        uint4 w = *reinterpret_cast<const uint4*>(xl0 + (size_t)s * D1 + c0);
        EDGE(w, valid);
    }
#undef EDGE

    H2U u01, u23, u45, u67;
    u01.v = a01; u23.v = a23; u45.v = a45; u67.v = a67;
    float2 f01 = __half22float2(u01.h), f23 = __half22float2(u23.h);
    float2 f45 = __half22float2(u45.h), f67 = __half22float2(u67.h);
    float acc0 = f01.x, acc1 = f01.y, acc2 = f23.x, acc3 = f23.y;
    float acc4 = f45.x, acc5 = f45.y, acc6 = f67.x, acc7 = f67.y;

#define COMB(V) V += __shfl_xor(V, 16); V += __shfl_xor(V, 32);
    COMB(acc0) COMB(acc1) COMB(acc2) COMB(acc3)
    COMB(acc4) COMB(acc5) COMB(acc6) COMB(acc7)
    COMB(wsum)
#undef COMB

    if (slot == 0) {
        float r = 1.f / (wsum + 1e-16f);
        float4 b0 = *reinterpret_cast<const float4*>(bias0 + c0);
        float4 b1 = *reinterpret_cast<const float4*>(bias0 + c0 + 4);
        float h[8];
        h[0] = fmaxf(acc0 * r + b0.x, 0.f);
        h[1] = fmaxf(acc1 * r + b0.y, 0.f);
        h[2] = fmaxf(acc2 * r + b0.z, 0.f);
        h[3] = fmaxf(acc3 * r + b0.w, 0.f);
        h[4] = fmaxf(acc4 * r + b1.x, 0.f);
        h[5] = fmaxf(acc5 * r + b1.y, 0.f);
        h[6] = fmaxf(acc6 * r + b1.z, 0.f);
        h[7] = fmaxf(acc7 * r + b1.w, 0.f);
        float pl0 = 0.f, pl1 = 0.f, pr0 = 0.f, pr1 = 0.f;
#pragma unroll
        for (int j = 0; j < 8; ++j) {
            float2 wl = *reinterpret_cast<const float2*>(Wl1 + (c0 + j) * 2);
            float2 wr = *reinterpret_cast<const float2*>(Wr1 + (c0 + j) * 2);
            pl0 += h[j] * wl.x; pl1 += h[j] * wl.y;
            pr0 += h[j] * wr.x; pr1 += h[j] * wr.y;
        }
#pragma unroll
        for (int ofs = 1; ofs < 16; ofs <<= 1) {
            pl0 += __shfl_xor(pl0, ofs);
            pl1 += __shfl_xor(pl1, ofs);
            pr0 += __shfl_xor(pr0, ofs);
            pr1 += __shfl_xor(pr1, ofs);
        }
        if (lane4 == 0) {
            *reinterpret_cast<float2*>(xl1 + (size_t)d * 2) =
                make_float2(pl0 + bl1[0], pl1 + bl1[1]);
            *reinterpret_cast<float2*>(xr1 + (size_t)d * 2) =
                make_float2(pr0 + br1[0], pr1 + br1[1]);
        }
    }
}

// ---- layer-1 fused: 4 lanes per dst; strided edges + 2-step shuffle combine
__global__ __launch_bounds__(256) void k_layer1(
    const int* __restrict__ rowst, const unsigned short* __restrict__ csr,
    const float* __restrict__ xl1, const float* __restrict__ xr1,
    const float* __restrict__ att1, const float* __restrict__ bias1,
    float* __restrict__ out)
{
    const int d = (blockIdx.x * 256 + threadIdx.x) >> 2;
    const int sub = threadIdx.x & 3;
    if (d >= NN) return;
    float2 xr = *reinterpret_cast<const float2*>(xr1 + (size_t)d * 2);
    float A0 = att1[0], A1 = att1[1];
    const int rs = rowst[d], re = rowst[d + 1];
    float sum = 0.f, a0 = 0.f, a1 = 0.f;
    for (int i = rs + sub; i < re; i += 4) {
        int s = csr[i];
        float2 xs = *reinterpret_cast<const float2*>(xl1 + (size_t)s * 2);
        float wgt = __expf(lrelu(xs.x + xr.x) * A0 + lrelu(xs.y + xr.y) * A1);
        sum += wgt;
        a0 += wgt * xs.x;
        a1 += wgt * xs.y;
    }
    sum += __shfl_xor(sum, 1); sum += __shfl_xor(sum, 2);
    a0  += __shfl_xor(a0, 1);  a0  += __shfl_xor(a0, 2);
    a1  += __shfl_xor(a1, 1);  a1  += __shfl_xor(a1, 2);
    if (sub == 0) {
        float r = 1.f / (sum + 1e-16f);
        out[(size_t)d * 2]     = a0 * r + bias1[0];
        out[(size_t)d * 2 + 1] = a1 * r + bias1[1];
    }
}

extern "C" void kernel_launch(void* const* d_in, const int* in_sizes, int n_in,
                              void* d_out, int out_size, void* d_ws, size_t ws_size,
                              hipStream_t stream)
{
    const float* x     = (const float*)d_in[0];
    const int*   ei    = (const int*)d_in[1];
    const int*   ts    = (const int*)d_in[2];
    const float* Wt    = (const float*)d_in[3];
    const float* Wl0   = (const float*)d_in[4];
    const float* bl0   = (const float*)d_in[5];
    const float* Wr0   = (const float*)d_in[6];
    const float* br0   = (const float*)d_in[7];
    const float* att0  = (const float*)d_in[8];
    const float* bias0 = (const float*)d_in[9];
    const float* Wl1   = (const float*)d_in[10];
    const float* bl1   = (const float*)d_in[11];
    const float* Wr1   = (const float*)d_in[12];
    const float* br1   = (const float*)d_in[13];
    const float* att1  = (const float*)d_in[14];
    const float* bias1 = (const float*)d_in[15];
    float* out = (float*)d_out;

    char* wsp = (char*)d_ws;
    size_t off = 0;
    auto alloc = [&](size_t bytes) -> void* {
        void* p = wsp + off;
        off += (bytes + 255) & ~(size_t)255;
        return p;
    };
    __half* xl0  = (__half*)alloc((size_t)NN * D1 * 2);
    __half* xr0  = (__half*)alloc((size_t)NN * D1 * 2);
    float* xl1   = (float*)alloc((size_t)NN * 2 * 4);
    float* xr1   = (float*)alloc((size_t)NN * 2 * 4);
    int* rowst   = (int*)alloc((size_t)(NN + 1) * 4);
    unsigned short* csr = (unsigned short*)alloc((size_t)EP * 2);
    int* gcnt        = (int*)alloc((size_t)NCB * 4);
    unsigned* cstage = (unsigned*)alloc((size_t)NCB * GCAP * 4);
    __half* Btg      = (__half*)alloc((size_t)256 * INDIM * 2);
    float* bcat      = (float*)alloc((size_t)256 * 4);

    k_wcast<<<(256 * INDIM + 255) / 256, 256, 0, stream>>>(Wl0, Wr0, bl0, br0, Btg, bcat, gcnt);

    const int nfused = 2 * ((NGEMM > NPTILES) ? NGEMM : NPTILES);
    k_g0p<<<nfused, 256, 0, stream>>>(x, ts, Wt, Btg, bcat, xl0, xr0, ei, gcnt, cstage);

    k_build2<<<NCB, 1024, 0, stream>>>(gcnt, cstage, rowst, csr);

    k_agg0<<<(NN + 3) / 4, 256, 0, stream>>>(rowst, csr, xl0, xr0, att0, bias0,
                                             Wl1, bl1, Wr1, br1, xl1, xr1);
    k_layer1<<<(NN * 4 + 255) / 256, 256, 0, stream>>>(rowst, csr, xl1, xr1, att1, bias1, out);
}